// Round 15
// baseline (189.217 us; speedup 1.0000x reference)
//
#include <hip/hip_runtime.h>
#include <math.h>

#define NT 16384
#define DM 2048
#define NE 64
#define TOPK 8
#define LTAX 0.04f
#define HYST 0.1f
#define ALPHA 0.7f

typedef unsigned int u32;
typedef unsigned short u16;
typedef unsigned long long u64;
typedef __attribute__((ext_vector_type(8))) short bf16x8;
typedef __attribute__((ext_vector_type(4))) float f32x4;

__device__ __forceinline__ float warp4_sum(float v) {
  v += __shfl_xor(v, 1); v += __shfl_xor(v, 2); return v;
}
__device__ __forceinline__ float warp4_max(float v) {
  v = fmaxf(v, __shfl_xor(v, 1)); v = fmaxf(v, __shfl_xor(v, 2)); return v;
}
__device__ __forceinline__ u16 f2bf(float f) {   // RNE f32->bf16
  u32 u = __float_as_uint(f);
  return (u16)((u + 0x7fffu + ((u >> 16) & 1u)) >> 16);
}
__device__ __forceinline__ float bf2f(u16 h) { return __uint_as_float(((u32)h) << 16); }

__device__ __forceinline__ void split3(float a, short& h, short& m, short& l) {
  u16 hh = f2bf(a);  float r1 = a - bf2f(hh);     // exact (Sterbenz)
  u16 mm = f2bf(r1); float r2 = r1 - bf2f(mm);    // exact
  h = (short)hh; m = (short)mm; l = (short)f2bf(r2);
}

// fixed-point 2^32: exact-commutative integer atomics => deterministic
__device__ __forceinline__ u64 to_fx(float v) {
  return (u64)__double2ll_rn((double)v * 4294967296.0);
}

// ---------------- K0: W -> MFMA-fragment-ordered bf16 splits + zero ---------
// Wpack[fi=c4*4+eb][sp=0..2][lane*8+j] = split_sp(W[eb*16+(lane&15)][c4*32+(lane>>4)*8+j])
// Each B-fragment load in k_gemm is then one contiguous uint4 per lane (L2-hot).
__global__ void k_init(const float* __restrict__ W, u16* __restrict__ Wpack,
                       u64* __restrict__ zp) {
  const int bid = blockIdx.x, tid = threadIdx.x;
  if (bid < 64) {
    int gid = bid * 256 + tid;          // 0..16383
    int lane = gid & 63;
    int fi = gid >> 6;                  // 0..255 = c4*4 + eb
    int eb = fi & 3, c4 = fi >> 2;
    int e = eb * 16 + (lane & 15);
    int k = c4 * 32 + (lane >> 4) * 8;
    const float* wp = W + (size_t)e * DM + k;
    float4 a = *(const float4*)wp;
    float4 bq = *(const float4*)(wp + 4);
    short ha[8], ma[8], la[8];
    split3(a.x, ha[0], ma[0], la[0]);
    split3(a.y, ha[1], ma[1], la[1]);
    split3(a.z, ha[2], ma[2], la[2]);
    split3(a.w, ha[3], ma[3], la[3]);
    split3(bq.x, ha[4], ma[4], la[4]);
    split3(bq.y, ha[5], ma[5], la[5]);
    split3(bq.z, ha[6], ma[6], la[6]);
    split3(bq.w, ha[7], ma[7], la[7]);
    bf16x8 h8, m8, l8;
#pragma unroll
    for (int z = 0; z < 8; z++) { h8[z] = ha[z]; m8[z] = ma[z]; l8[z] = la[z]; }
    u16* dst = Wpack + (size_t)fi * 1536 + lane * 8;
    *(bf16x8*)(dst) = h8;
    *(bf16x8*)(dst + 512) = m8;
    *(bf16x8*)(dst + 1024) = l8;
  } else {
    int i = (bid - 64) * 256 + tid;
    if (i < 26624) zp[i] = 0ull;
  }
}

// ---------------- K1: LDS-free, barrier-free MFMA GEMM, split-K=4 -----------
// 1024 blocks. A-frags loaded directly from x (coalesced 128B/row), split3 in
// registers; B-frags are contiguous uint4 loads from L2-resident Wpack.
// f64 in-register flush every 8 chunks (fixed order -> deterministic).
__launch_bounds__(256)
__global__ void k_gemm(const float* __restrict__ x, const u16* __restrict__ Wpack,
                       float* __restrict__ Lpart) {
  const int tid = threadIdx.x, bid = blockIdx.x;
  const int tile = bid >> 2, ks = bid & 3;
  const int row0 = tile * 64;
  const int k0 = ks * 512;
  const int lane = tid & 63, w = tid >> 6;
  const int l15 = lane & 15, l4 = lane >> 4;

  f32x4 accA[4], accB[4];
  double accD[4][4];
#pragma unroll
  for (int eb = 0; eb < 4; eb++) {
    accA[eb] = (f32x4)0.f; accB[eb] = (f32x4)0.f;
#pragma unroll
    for (int r = 0; r < 4; r++) accD[eb][r] = 0.0;
  }

  const float* xp = x + (size_t)(row0 + w * 16 + l15) * DM + k0 + l4 * 8;
  const u16* wp = Wpack + (size_t)(k0 >> 5) * 6144 + lane * 8;

#pragma unroll 1
  for (int t = 0; t < 16; t++) {
    float4 xq0 = *(const float4*)(xp + t * 32);
    float4 xq1 = *(const float4*)(xp + t * 32 + 4);
    short ha[8], ma[8], la[8];
    split3(xq0.x, ha[0], ma[0], la[0]);
    split3(xq0.y, ha[1], ma[1], la[1]);
    split3(xq0.z, ha[2], ma[2], la[2]);
    split3(xq0.w, ha[3], ma[3], la[3]);
    split3(xq1.x, ha[4], ma[4], la[4]);
    split3(xq1.y, ha[5], ma[5], la[5]);
    split3(xq1.z, ha[6], ma[6], la[6]);
    split3(xq1.w, ha[7], ma[7], la[7]);
    bf16x8 ah, am, al;
#pragma unroll
    for (int z = 0; z < 8; z++) { ah[z] = ha[z]; am[z] = ma[z]; al[z] = la[z]; }
    const u16* wc = wp + t * 6144;
#pragma unroll
    for (int eb = 0; eb < 4; eb++) {
      bf16x8 bh = *(const bf16x8*)(wc + (eb * 3 + 0) * 512);
      bf16x8 bm = *(const bf16x8*)(wc + (eb * 3 + 1) * 512);
      bf16x8 bl = *(const bf16x8*)(wc + (eb * 3 + 2) * 512);
      accA[eb] = __builtin_amdgcn_mfma_f32_16x16x32_bf16(ah, bh, accA[eb], 0, 0, 0);
      accB[eb] = __builtin_amdgcn_mfma_f32_16x16x32_bf16(ah, bm, accB[eb], 0, 0, 0);
      accB[eb] = __builtin_amdgcn_mfma_f32_16x16x32_bf16(am, bh, accB[eb], 0, 0, 0);
      accB[eb] = __builtin_amdgcn_mfma_f32_16x16x32_bf16(am, bm, accB[eb], 0, 0, 0);
      accB[eb] = __builtin_amdgcn_mfma_f32_16x16x32_bf16(ah, bl, accB[eb], 0, 0, 0);
      accB[eb] = __builtin_amdgcn_mfma_f32_16x16x32_bf16(al, bh, accB[eb], 0, 0, 0);
    }
    if ((t & 7) == 7) {
#pragma unroll
      for (int eb = 0; eb < 4; eb++) {
#pragma unroll
        for (int r = 0; r < 4; r++)
          accD[eb][r] += (double)accA[eb][r] + (double)accB[eb][r];
        accA[eb] = (f32x4)0.f; accB[eb] = (f32x4)0.f;
      }
    }
  }

  // C/D layout: col=lane&15 (expert block col), row=(lane>>4)*4+reg (verified)
  float* outp = Lpart + (size_t)ks * NT * NE;
#pragma unroll
  for (int eb = 0; eb < 4; eb++)
#pragma unroll
    for (int r = 0; r < 4; r++) {
      int trow = w * 16 + l4 * 4 + r;
      outp[(size_t)(row0 + trow) * NE + eb * 16 + l15] = (float)accD[eb][r];
    }
}

// ---------------- K2: reduce 4 partials + center + softmax1 + gram ----------
__launch_bounds__(256)
__global__ void k_post(const float* __restrict__ Lpart, const float* __restrict__ b,
                       float* __restrict__ Lbuf, u64* __restrict__ CmAcc) {
  __shared__ float ms[64 * 68];
  const int tid = threadIdx.x, bid = blockIdx.x;
  const int tg = tid >> 2, q = tid & 3;
  const int row = bid * 64 + tg;
  float l[16], m[16];
  {
    const float* p0 = Lpart + (size_t)row * NE + q * 16;
    const float* p1 = p0 + (size_t)NT * NE;
    const float* p2 = p1 + (size_t)NT * NE;
    const float* p3 = p2 + (size_t)NT * NE;
#pragma unroll
    for (int i = 0; i < 4; i++) {
      float4 bv = *(const float4*)(b + q * 16 + i * 4);
      float4 v0 = *(const float4*)(p0 + i * 4);
      float4 v1 = *(const float4*)(p1 + i * 4);
      float4 v2 = *(const float4*)(p2 + i * 4);
      float4 v3 = *(const float4*)(p3 + i * 4);
      l[i * 4 + 0] = (float)((double)v0.x + (double)v1.x + (double)v2.x + (double)v3.x) + bv.x;
      l[i * 4 + 1] = (float)((double)v0.y + (double)v1.y + (double)v2.y + (double)v3.y) + bv.y;
      l[i * 4 + 2] = (float)((double)v0.z + (double)v1.z + (double)v2.z + (double)v3.z) + bv.z;
      l[i * 4 + 3] = (float)((double)v0.w + (double)v1.w + (double)v2.w + (double)v3.w) + bv.w;
    }
    float s = 0.f;
#pragma unroll
    for (int j = 0; j < 16; j++) s += l[j];
    s = warp4_sum(s);
    const float mean = s * (1.0f / 64.0f);
    float mx = -1e30f;
#pragma unroll
    for (int j = 0; j < 16; j++) { l[j] -= mean; mx = fmaxf(mx, l[j]); }
    mx = warp4_max(mx);
#pragma unroll
    for (int i = 0; i < 4; i++)
      *(float4*)(Lbuf + (size_t)row * NE + q * 16 + i * 4) =
          make_float4(l[i * 4], l[i * 4 + 1], l[i * 4 + 2], l[i * 4 + 3]);
    float ps = 0.f;
#pragma unroll
    for (int j = 0; j < 16; j++) { m[j] = expf(l[j] - mx); ps += m[j]; }
    ps = warp4_sum(ps);
    const float inv = 1.0f / ps;
#pragma unroll
    for (int j = 0; j < 16; j++) m[j] *= inv;
#pragma unroll
    for (int i = 0; i < 4; i++)
      *(float4*)(ms + tg * 68 + q * 16 + i * 4) =
          make_float4(m[i * 4], m[i * 4 + 1], m[i * 4 + 2], m[i * 4 + 3]);
  }
  __syncthreads();
  // gram partial -> slotted fx atomics (slot = bid & 3)
  const int gi0 = (tid >> 4) * 4;
  const int gj0 = (tid & 15) * 4;
  float ga[4][4];
#pragma unroll
  for (int a = 0; a < 4; a++)
#pragma unroll
    for (int c = 0; c < 4; c++) ga[a][c] = 0.f;
  for (int t = 0; t < 64; t++) {
    float4 a = *(const float4*)(ms + t * 68 + gi0);
    float4 bb = *(const float4*)(ms + t * 68 + gj0);
    ga[0][0] = fmaf(a.x, bb.x, ga[0][0]); ga[0][1] = fmaf(a.x, bb.y, ga[0][1]);
    ga[0][2] = fmaf(a.x, bb.z, ga[0][2]); ga[0][3] = fmaf(a.x, bb.w, ga[0][3]);
    ga[1][0] = fmaf(a.y, bb.x, ga[1][0]); ga[1][1] = fmaf(a.y, bb.y, ga[1][1]);
    ga[1][2] = fmaf(a.y, bb.z, ga[1][2]); ga[1][3] = fmaf(a.y, bb.w, ga[1][3]);
    ga[2][0] = fmaf(a.z, bb.x, ga[2][0]); ga[2][1] = fmaf(a.z, bb.y, ga[2][1]);
    ga[2][2] = fmaf(a.z, bb.z, ga[2][2]); ga[2][3] = fmaf(a.z, bb.w, ga[2][3]);
    ga[3][0] = fmaf(a.w, bb.x, ga[3][0]); ga[3][1] = fmaf(a.w, bb.y, ga[3][1]);
    ga[3][2] = fmaf(a.w, bb.z, ga[3][2]); ga[3][3] = fmaf(a.w, bb.w, ga[3][3]);
  }
  u64* slot = CmAcc + (size_t)(bid & 3) * 4096;
#pragma unroll
  for (int ii = 0; ii < 4; ii++)
#pragma unroll
    for (int jj = 0; jj < 4; jj++)
      atomicAdd(slot + (gi0 + ii) * 64 + gj0 + jj, to_fx(ga[ii][jj]));
}

// ---------------- K3: correction + softmax2 -> M0; emit P0 ------------------
__launch_bounds__(256)
__global__ void k_correct(const float* __restrict__ Lbuf, const u64* __restrict__ CmAcc,
                          float* __restrict__ M0, u64* __restrict__ p0Acc) {
  __shared__ float ms[64 * 68];
  __shared__ float Cs[4096];
  __shared__ float cred[256];
  const int tid = threadIdx.x, bid = blockIdx.x;
  const int tg = tid >> 2, q = tid & 3;
  const int lane = tid & 63, w = tid >> 6;
  const int row = bid * 64 + tg;
  float l[16], m[16];
#pragma unroll
  for (int i = 0; i < 4; i++) {
    float4 lv = *(const float4*)(Lbuf + (size_t)row * NE + q * 16 + i * 4);
    l[i * 4 + 0] = lv.x; l[i * 4 + 1] = lv.y; l[i * 4 + 2] = lv.z; l[i * 4 + 3] = lv.w;
  }
  // recompute softmax1 (same op order on identical values as k_post)
  {
    float mx = -1e30f;
#pragma unroll
    for (int j = 0; j < 16; j++) mx = fmaxf(mx, l[j]);
    mx = warp4_max(mx);
    float ps = 0.f;
#pragma unroll
    for (int j = 0; j < 16; j++) { m[j] = expf(l[j] - mx); ps += m[j]; }
    ps = warp4_sum(ps);
    const float inv = 1.0f / ps;
#pragma unroll
    for (int j = 0; j < 16; j++) m[j] *= inv;
#pragma unroll
    for (int i = 0; i < 4; i++)
      *(float4*)(ms + tg * 68 + q * 16 + i * 4) =
          make_float4(m[i * 4], m[i * 4 + 1], m[i * 4 + 2], m[i * 4 + 3]);
  }
  // C from 4 slots (plain loads: kernel boundary = acquire), zero diag
#pragma unroll 4
  for (int i = 0; i < 16; i++) {
    int idx = tid + i * 256;
    u64 s = CmAcc[idx] + CmAcc[4096 + idx] + CmAcc[8192 + idx] + CmAcc[12288 + idx];
    float v = (float)((double)s * (1.0 / 4294967296.0));
    int r = idx >> 6, c = idx & 63;
    Cs[idx] = (r == c) ? 0.f : v;
  }
  __syncthreads();
  // correction + softmax2
  {
    float g[16];
#pragma unroll
    for (int j = 0; j < 16; j++) g[j] = 0.f;
    for (int f = 0; f < 64; f++) {
      float mf = ms[tg * 68 + f];
#pragma unroll
      for (int i = 0; i < 4; i++) {
        float4 cv = *(const float4*)(Cs + f * 64 + q * 16 + i * 4);
        g[i * 4 + 0] = fmaf(mf, cv.x, g[i * 4 + 0]);
        g[i * 4 + 1] = fmaf(mf, cv.y, g[i * 4 + 1]);
        g[i * 4 + 2] = fmaf(mf, cv.z, g[i * 4 + 2]);
        g[i * 4 + 3] = fmaf(mf, cv.w, g[i * 4 + 3]);
      }
    }
    float dot = 0.f;
#pragma unroll
    for (int j = 0; j < 16; j++) { g[j] *= 4.f; dot += m[j] * g[j]; }
    dot = warp4_sum(dot);
    float mx = -1e30f;
#pragma unroll
    for (int j = 0; j < 16; j++) {
      l[j] = l[j] - LTAX * (m[j] * (g[j] - dot));
      mx = fmaxf(mx, l[j]);
    }
    mx = warp4_max(mx);
    float ps = 0.f;
#pragma unroll
    for (int j = 0; j < 16; j++) { m[j] = expf(l[j] - mx); ps += m[j]; }
    ps = warp4_sum(ps);
    const float inv = 1.0f / ps;
#pragma unroll
    for (int j = 0; j < 16; j++) m[j] *= inv;
#pragma unroll
    for (int i = 0; i < 4; i++)
      *(float4*)(M0 + (size_t)row * NE + q * 16 + i * 4) =
          make_float4(m[i * 4], m[i * 4 + 1], m[i * 4 + 2], m[i * 4 + 3]);
  }
  // P0 partial
  {
    float cs[16];
#pragma unroll
    for (int j = 0; j < 16; j++) cs[j] = m[j];
#pragma unroll
    for (int j = 0; j < 16; j++) {
      cs[j] += __shfl_xor(cs[j], 4);  cs[j] += __shfl_xor(cs[j], 8);
      cs[j] += __shfl_xor(cs[j], 16); cs[j] += __shfl_xor(cs[j], 32);
    }
    if ((lane >> 2) == 0) {
#pragma unroll
      for (int j = 0; j < 16; j++) cred[w * 64 + lane * 16 + j] = cs[j];
    }
    __syncthreads();
    if (tid < 64)
      atomicAdd(p0Acc + (size_t)(bid & 15) * 64 + tid,
                to_fx(cred[tid] + cred[64 + tid] + cred[128 + tid] + cred[192 + tid]));
  }
}

// ---------------- K4: one factored Sinkhorn iteration -----------------------
__launch_bounds__(256)
__global__ void k_sink(const float* __restrict__ M0, const u64* __restrict__ pin,
                       u64* __restrict__ pout) {
  __shared__ u64 pred[4][64];
  __shared__ float fac[64];
  __shared__ float cred[256];
  const int tid = threadIdx.x, bid = blockIdx.x;
  const int tg = tid >> 2, q = tid & 3;
  const int lane = tid & 63, w = tid >> 6;
  const int row = bid * 64 + tg;
  {
    const int grp = tid >> 6, e = tid & 63;
    pred[grp][e] = pin[grp * 64 + e] + pin[(grp + 4) * 64 + e] +
                   pin[(grp + 8) * 64 + e] + pin[(grp + 12) * 64 + e];
  }
  __syncthreads();
  if (tid < 64) {
    u64 s = pred[0][tid] + pred[1][tid] + pred[2][tid] + pred[3][tid];
    float P = (float)((double)s * (1.0 / 4294967296.0));
    fac[tid] = 256.0f / fmaxf(P, 1e-30f);     // V(e)
  }
  __syncthreads();
  float mv[16];
#pragma unroll
  for (int i = 0; i < 4; i++) {
    float4 v = *(const float4*)(M0 + (size_t)row * NE + q * 16 + i * 4);
    mv[i * 4 + 0] = v.x; mv[i * 4 + 1] = v.y; mv[i * 4 + 2] = v.z; mv[i * 4 + 3] = v.w;
  }
  float Q = 0.f;
#pragma unroll
  for (int j = 0; j < 16; j++) Q = fmaf(mv[j], fac[q * 16 + j], Q);
  Q = warp4_sum(Q);
  const float U = 1.0f / fmaxf(Q, 1e-30f);
  float cs[16];
#pragma unroll
  for (int j = 0; j < 16; j++) cs[j] = U * mv[j];
#pragma unroll
  for (int j = 0; j < 16; j++) {
    cs[j] += __shfl_xor(cs[j], 4);  cs[j] += __shfl_xor(cs[j], 8);
    cs[j] += __shfl_xor(cs[j], 16); cs[j] += __shfl_xor(cs[j], 32);
  }
  if ((lane >> 2) == 0) {
#pragma unroll
    for (int j = 0; j < 16; j++) cred[w * 64 + lane * 16 + j] = cs[j];
  }
  __syncthreads();
  if (tid < 64)
    atomicAdd(pout + (size_t)(bid & 15) * 64 + tid,
              to_fx(cred[tid] + cred[64 + tid] + cred[128 + tid] + cred[192 + tid]));
}

// ---------------- K5: final M10 + damping + hysteresis + topk ---------------
__launch_bounds__(256)
__global__ void k_final(const float* __restrict__ M0, const u64* __restrict__ pin,
                        const float* __restrict__ pp, const void* __restrict__ pmask,
                        float* __restrict__ out) {
  __shared__ u64 pred[4][64];
  __shared__ float fac[64];
  __shared__ int s_cnt[256];
  __shared__ int s_flag;
  const int tid = threadIdx.x, bid = blockIdx.x;
  const int tg = tid >> 2, q = tid & 3;
  const int lane = tid & 63;
  const int row = bid * 64 + tg;

  // prev_mask format detect (first 4096 bytes): u8->512, f32->256, i32->128
  {
    uint4 v = ((const uint4*)pmask)[tid];
    int c = 0; u32 ww;
    ww = v.x; c += ((ww & 0xffu) != 0) + ((ww & 0xff00u) != 0) + ((ww & 0xff0000u) != 0) + ((ww & 0xff000000u) != 0);
    ww = v.y; c += ((ww & 0xffu) != 0) + ((ww & 0xff00u) != 0) + ((ww & 0xff0000u) != 0) + ((ww & 0xff000000u) != 0);
    ww = v.z; c += ((ww & 0xffu) != 0) + ((ww & 0xff00u) != 0) + ((ww & 0xff0000u) != 0) + ((ww & 0xff000000u) != 0);
    ww = v.w; c += ((ww & 0xffu) != 0) + ((ww & 0xff00u) != 0) + ((ww & 0xff0000u) != 0) + ((ww & 0xff000000u) != 0);
    s_cnt[tid] = c;
    __syncthreads();
    for (int s = 128; s; s >>= 1) { if (tid < s) s_cnt[tid] += s_cnt[tid + s]; __syncthreads(); }
    if (tid == 0) { int n = s_cnt[0]; s_flag = (n > 384) ? 0 : ((n > 192) ? 2 : 1); }
  }
  {
    const int grp = tid >> 6, e = tid & 63;
    pred[grp][e] = pin[grp * 64 + e] + pin[(grp + 4) * 64 + e] +
                   pin[(grp + 8) * 64 + e] + pin[(grp + 12) * 64 + e];
  }
  __syncthreads();
  if (tid < 64) {
    u64 s = pred[0][tid] + pred[1][tid] + pred[2][tid] + pred[3][tid];
    float P = (float)((double)s * (1.0 / 4294967296.0));
    fac[tid] = 256.0f / fmaxf(P, 1e-30f);     // V10
  }
  __syncthreads();

  float mv[16];
#pragma unroll
  for (int i = 0; i < 4; i++) {
    float4 v = *(const float4*)(M0 + (size_t)row * NE + q * 16 + i * 4);
    mv[i * 4 + 0] = v.x; mv[i * 4 + 1] = v.y; mv[i * 4 + 2] = v.z; mv[i * 4 + 3] = v.w;
  }
  float Q = 0.f;
#pragma unroll
  for (int j = 0; j < 16; j++) Q = fmaf(mv[j], fac[q * 16 + j], Q);
  Q = warp4_sum(Q);
  const float U = 1.0f / fmaxf(Q, 1e-30f);
  float m[16];
#pragma unroll
  for (int j = 0; j < 16; j++) m[j] = U * mv[j] * fac[q * 16 + j];   // M10 row

  const int flag = s_flag;
  float pv[16], mk[16];
#pragma unroll
  for (int i = 0; i < 4; i++) {
    float4 v = *(const float4*)(pp + (size_t)row * NE + q * 16 + i * 4);
    pv[i * 4 + 0] = v.x; pv[i * 4 + 1] = v.y; pv[i * 4 + 2] = v.z; pv[i * 4 + 3] = v.w;
  }
  if (flag == 0) {
    const u32* pb = (const u32*)pmask + row * 16 + q * 4;
#pragma unroll
    for (int i = 0; i < 4; i++) {
      u32 ww = pb[i];
      mk[i * 4 + 0] = (ww & 0xffu) ? 1.f : 0.f;
      mk[i * 4 + 1] = (ww & 0xff00u) ? 1.f : 0.f;
      mk[i * 4 + 2] = (ww & 0xff0000u) ? 1.f : 0.f;
      mk[i * 4 + 3] = (ww & 0xff000000u) ? 1.f : 0.f;
    }
  } else if (flag == 1) {
    const int* pb = (const int*)pmask + (size_t)row * NE + q * 16;
#pragma unroll
    for (int j = 0; j < 16; j++) mk[j] = pb[j] ? 1.f : 0.f;
  } else {
    const float* pb = (const float*)pmask + (size_t)row * NE + q * 16;
#pragma unroll
    for (int j = 0; j < 16; j++) mk[j] = (pb[j] != 0.f) ? 1.f : 0.f;
  }
  float msum = 0.f;
#pragma unroll
  for (int j = 0; j < 16; j++) msum += mk[j];
  msum = warp4_sum(msum);
  const float hscale = HYST / fmaxf(msum, 1.0f);
  float v[16];
  float s = 0.f;
#pragma unroll
  for (int j = 0; j < 16; j++) {
    float base = (1.f - ALPHA) * pv[j] + ALPHA * m[j];
    v[j] = (1.f - HYST) * base + hscale * mk[j];
    s += v[j];
  }
  s = warp4_sum(s);
  const float inv = 1.0f / fmaxf(s, 1e-12f);
#pragma unroll
  for (int j = 0; j < 16; j++) v[j] *= inv;

  float* mout = out;
  float* kout = out + (size_t)NT * NE;
#pragma unroll
  for (int i = 0; i < 4; i++)
    *(float4*)(mout + (size_t)row * NE + q * 16 + i * 4) =
        make_float4(v[i * 4], v[i * 4 + 1], v[i * 4 + 2], v[i * 4 + 3]);

  int cnt[16];
#pragma unroll
  for (int j = 0; j < 16; j++) cnt[j] = 0;
  const int base = lane & ~3;
#pragma unroll
  for (int oq = 0; oq < 4; oq++) {
#pragma unroll
    for (int j2 = 0; j2 < 16; j2++) {
      float ov = __shfl(v[j2], base + oq, 64);
      int oe = oq * 16 + j2;
#pragma unroll
      for (int j = 0; j < 16; j++) {
        int me = q * 16 + j;
        if (ov > v[j] || (ov == v[j] && oe < me)) cnt[j]++;
      }
    }
  }
#pragma unroll
  for (int i = 0; i < 4; i++)
    *(float4*)(kout + (size_t)row * NE + q * 16 + i * 4) =
        make_float4(cnt[i * 4] < TOPK ? 1.f : 0.f, cnt[i * 4 + 1] < TOPK ? 1.f : 0.f,
                    cnt[i * 4 + 2] < TOPK ? 1.f : 0.f, cnt[i * 4 + 3] < TOPK ? 1.f : 0.f);
}

extern "C" void kernel_launch(void* const* d_in, const int* in_sizes, int n_in,
                              void* d_out, int out_size, void* d_ws, size_t ws_size,
                              hipStream_t stream) {
  const float* x = (const float*)d_in[0];
  const float* W = (const float*)d_in[1];
  const float* b = (const float*)d_in[2];
  const float* pp = (const float*)d_in[3];
  const void* pmask = d_in[4];
  float* out = (float*)d_out;

  unsigned char* wsb = (unsigned char*)d_ws;
  u16* Wpack = (u16*)(wsb);                       // 768 KB
  float* Lpart = (float*)(wsb + 786432);          // 4 * NT*NE f32 = 16 MB -> 17563648
  float* Lbuf = (float*)(wsb + 17563648);         // 4 MB -> 21757952
  float* M0buf = (float*)(wsb + 21757952);        // 4 MB -> 25952256
  u64* CmAcc = (u64*)(wsb + 25952256);            // 4 slots * 4096 u64 = 128 KB
  u64* pAcc = (u64*)(wsb + 26083328);             // 10 * 16 * 64 u64 = 80 KB

  k_init<<<168, 256, 0, stream>>>(W, Wpack, CmAcc);   // pack W + zero 26624 u64
  k_gemm<<<1024, 256, 0, stream>>>(x, Wpack, Lpart);
  k_post<<<256, 256, 0, stream>>>(Lpart, b, Lbuf, CmAcc);
  k_correct<<<256, 256, 0, stream>>>(Lbuf, CmAcc, M0buf, pAcc);
  for (int k = 1; k <= 9; k++)
    k_sink<<<256, 256, 0, stream>>>(M0buf, pAcc + (size_t)(k - 1) * 1024,
                                    pAcc + (size_t)k * 1024);
  k_final<<<256, 256, 0, stream>>>(M0buf, pAcc + (size_t)9 * 1024, pp, pmask, out);
}

// Round 16
// 186.616 us; speedup vs baseline: 1.0139x; 1.0139x over previous
//
#include <hip/hip_runtime.h>
#include <math.h>

#define NT 16384
#define DM 2048
#define NE 64
#define TOPK 8
#define LTAX 0.04f
#define HYST 0.1f
#define ALPHA 0.7f

typedef unsigned int u32;
typedef unsigned short u16;
typedef unsigned long long u64;
typedef __attribute__((ext_vector_type(8))) short bf16x8;
typedef __attribute__((ext_vector_type(4))) float f32x4;

__device__ __forceinline__ float warp4_sum(float v) {
  v += __shfl_xor(v, 1); v += __shfl_xor(v, 2); return v;
}
__device__ __forceinline__ float warp4_max(float v) {
  v = fmaxf(v, __shfl_xor(v, 1)); v = fmaxf(v, __shfl_xor(v, 2)); return v;
}
__device__ __forceinline__ u16 f2bf(float f) {   // RNE f32->bf16
  u32 u = __float_as_uint(f);
  return (u16)((u + 0x7fffu + ((u >> 16) & 1u)) >> 16);
}
__device__ __forceinline__ float bf2f(u16 h) { return __uint_as_float(((u32)h) << 16); }

__device__ __forceinline__ void split3(float a, short& h, short& m, short& l) {
  u16 hh = f2bf(a);  float r1 = a - bf2f(hh);     // exact (Sterbenz)
  u16 mm = f2bf(r1); float r2 = r1 - bf2f(mm);    // exact
  h = (short)hh; m = (short)mm; l = (short)f2bf(r2);
}

// fixed-point 2^32: exact-commutative integer atomics => deterministic
__device__ __forceinline__ u64 to_fx(float v) {
  return (u64)__double2ll_rn((double)v * 4294967296.0);
}

// ---------------- K0: W -> MFMA-fragment-ordered bf16 splits + zero ---------
__global__ void k_init(const float* __restrict__ W, u16* __restrict__ Wpack,
                       u64* __restrict__ zp) {
  const int bid = blockIdx.x, tid = threadIdx.x;
  if (bid < 64) {
    int gid = bid * 256 + tid;          // 0..16383
    int lane = gid & 63;
    int fi = gid >> 6;                  // 0..255 = c4*4 + eb
    int eb = fi & 3, c4 = fi >> 2;
    int e = eb * 16 + (lane & 15);
    int k = c4 * 32 + (lane >> 4) * 8;
    const float* wp = W + (size_t)e * DM + k;
    float4 a = *(const float4*)wp;
    float4 bq = *(const float4*)(wp + 4);
    short ha[8], ma[8], la[8];
    split3(a.x, ha[0], ma[0], la[0]);
    split3(a.y, ha[1], ma[1], la[1]);
    split3(a.z, ha[2], ma[2], la[2]);
    split3(a.w, ha[3], ma[3], la[3]);
    split3(bq.x, ha[4], ma[4], la[4]);
    split3(bq.y, ha[5], ma[5], la[5]);
    split3(bq.z, ha[6], ma[6], la[6]);
    split3(bq.w, ha[7], ma[7], la[7]);
    bf16x8 h8, m8, l8;
#pragma unroll
    for (int z = 0; z < 8; z++) { h8[z] = ha[z]; m8[z] = ma[z]; l8[z] = la[z]; }
    u16* dst = Wpack + (size_t)fi * 1536 + lane * 8;
    *(bf16x8*)(dst) = h8;
    *(bf16x8*)(dst + 512) = m8;
    *(bf16x8*)(dst + 1024) = l8;
  } else {
    int i = (bid - 64) * 256 + tid;
    if (i < 26624) zp[i] = 0ull;
  }
}

// ---------------- K1: LDS-free MFMA GEMM, split-K (4 or 8), pipelined -------
// grid = 256<<lg blocks. unroll-2 t-loop lets the compiler issue iter t+1's
// 12 L2 Wpack loads + 2 x loads under iter t's MFMAs (R15 was serialized).
__launch_bounds__(256)
__global__ void k_gemm(const float* __restrict__ x, const u16* __restrict__ Wpack,
                       float* __restrict__ Lpart, int lg) {
  const int tid = threadIdx.x, bid = blockIdx.x;
  const int tile = bid >> lg, ks = bid & ((1 << lg) - 1);
  const int row0 = tile * 64;
  const int klen = DM >> lg;
  const int k0 = ks * klen;
  const int nt = klen >> 5;
  const int lane = tid & 63, w = tid >> 6;
  const int l15 = lane & 15, l4 = lane >> 4;

  f32x4 accA[4], accB[4];
  double accD[4][4];
#pragma unroll
  for (int eb = 0; eb < 4; eb++) {
    accA[eb] = (f32x4)0.f; accB[eb] = (f32x4)0.f;
#pragma unroll
    for (int r = 0; r < 4; r++) accD[eb][r] = 0.0;
  }

  const float* xp = x + (size_t)(row0 + w * 16 + l15) * DM + k0 + l4 * 8;
  const u16* wp = Wpack + (size_t)(k0 >> 5) * 6144 + lane * 8;

#pragma unroll 2
  for (int t = 0; t < nt; t++) {
    float4 xq0 = *(const float4*)(xp + t * 32);
    float4 xq1 = *(const float4*)(xp + t * 32 + 4);
    short ha[8], ma[8], la[8];
    split3(xq0.x, ha[0], ma[0], la[0]);
    split3(xq0.y, ha[1], ma[1], la[1]);
    split3(xq0.z, ha[2], ma[2], la[2]);
    split3(xq0.w, ha[3], ma[3], la[3]);
    split3(xq1.x, ha[4], ma[4], la[4]);
    split3(xq1.y, ha[5], ma[5], la[5]);
    split3(xq1.z, ha[6], ma[6], la[6]);
    split3(xq1.w, ha[7], ma[7], la[7]);
    bf16x8 ah, am, al;
#pragma unroll
    for (int z = 0; z < 8; z++) { ah[z] = ha[z]; am[z] = ma[z]; al[z] = la[z]; }
    const u16* wc = wp + t * 6144;
#pragma unroll
    for (int eb = 0; eb < 4; eb++) {
      bf16x8 bh = *(const bf16x8*)(wc + (eb * 3 + 0) * 512);
      bf16x8 bm = *(const bf16x8*)(wc + (eb * 3 + 1) * 512);
      bf16x8 bl = *(const bf16x8*)(wc + (eb * 3 + 2) * 512);
      accA[eb] = __builtin_amdgcn_mfma_f32_16x16x32_bf16(ah, bh, accA[eb], 0, 0, 0);
      accB[eb] = __builtin_amdgcn_mfma_f32_16x16x32_bf16(ah, bm, accB[eb], 0, 0, 0);
      accB[eb] = __builtin_amdgcn_mfma_f32_16x16x32_bf16(am, bh, accB[eb], 0, 0, 0);
      accB[eb] = __builtin_amdgcn_mfma_f32_16x16x32_bf16(am, bm, accB[eb], 0, 0, 0);
      accB[eb] = __builtin_amdgcn_mfma_f32_16x16x32_bf16(ah, bl, accB[eb], 0, 0, 0);
      accB[eb] = __builtin_amdgcn_mfma_f32_16x16x32_bf16(al, bh, accB[eb], 0, 0, 0);
    }
    if ((t & 7) == 7 || t == nt - 1) {
#pragma unroll
      for (int eb = 0; eb < 4; eb++) {
#pragma unroll
        for (int r = 0; r < 4; r++)
          accD[eb][r] += (double)accA[eb][r] + (double)accB[eb][r];
        accA[eb] = (f32x4)0.f; accB[eb] = (f32x4)0.f;
      }
    }
  }

  // C/D layout: col=lane&15, row=(lane>>4)*4+reg (verified)
  float* outp = Lpart + (size_t)ks * NT * NE;
#pragma unroll
  for (int eb = 0; eb < 4; eb++)
#pragma unroll
    for (int r = 0; r < 4; r++) {
      int trow = w * 16 + l4 * 4 + r;
      outp[(size_t)(row0 + trow) * NE + eb * 16 + l15] = (float)accD[eb][r];
    }
}

// ---------------- K2: reduce partials + center + softmax1 + gram ------------
__launch_bounds__(256)
__global__ void k_post(const float* __restrict__ Lpart, const float* __restrict__ b,
                       float* __restrict__ Lbuf, u64* __restrict__ CmAcc, int splitk) {
  __shared__ float ms[64 * 68];
  const int tid = threadIdx.x, bid = blockIdx.x;
  const int tg = tid >> 2, q = tid & 3;
  const int row = bid * 64 + tg;
  float l[16], m[16];
  {
    double acc[16];
#pragma unroll
    for (int j = 0; j < 16; j++) acc[j] = 0.0;
    for (int ks = 0; ks < splitk; ks++) {
      const float* p = Lpart + (size_t)ks * NT * NE + (size_t)row * NE + q * 16;
#pragma unroll
      for (int i = 0; i < 4; i++) {
        float4 v = *(const float4*)(p + i * 4);
        acc[i * 4 + 0] += (double)v.x; acc[i * 4 + 1] += (double)v.y;
        acc[i * 4 + 2] += (double)v.z; acc[i * 4 + 3] += (double)v.w;
      }
    }
#pragma unroll
    for (int i = 0; i < 4; i++) {
      float4 bv = *(const float4*)(b + q * 16 + i * 4);
      l[i * 4 + 0] = (float)acc[i * 4 + 0] + bv.x;
      l[i * 4 + 1] = (float)acc[i * 4 + 1] + bv.y;
      l[i * 4 + 2] = (float)acc[i * 4 + 2] + bv.z;
      l[i * 4 + 3] = (float)acc[i * 4 + 3] + bv.w;
    }
    float s = 0.f;
#pragma unroll
    for (int j = 0; j < 16; j++) s += l[j];
    s = warp4_sum(s);
    const float mean = s * (1.0f / 64.0f);
    float mx = -1e30f;
#pragma unroll
    for (int j = 0; j < 16; j++) { l[j] -= mean; mx = fmaxf(mx, l[j]); }
    mx = warp4_max(mx);
#pragma unroll
    for (int i = 0; i < 4; i++)
      *(float4*)(Lbuf + (size_t)row * NE + q * 16 + i * 4) =
          make_float4(l[i * 4], l[i * 4 + 1], l[i * 4 + 2], l[i * 4 + 3]);
    float ps = 0.f;
#pragma unroll
    for (int j = 0; j < 16; j++) { m[j] = expf(l[j] - mx); ps += m[j]; }
    ps = warp4_sum(ps);
    const float inv = 1.0f / ps;
#pragma unroll
    for (int j = 0; j < 16; j++) m[j] *= inv;
#pragma unroll
    for (int i = 0; i < 4; i++)
      *(float4*)(ms + tg * 68 + q * 16 + i * 4) =
          make_float4(m[i * 4], m[i * 4 + 1], m[i * 4 + 2], m[i * 4 + 3]);
  }
  __syncthreads();
  // gram partial -> slotted fx atomics (slot = bid & 3)
  const int gi0 = (tid >> 4) * 4;
  const int gj0 = (tid & 15) * 4;
  float ga[4][4];
#pragma unroll
  for (int a = 0; a < 4; a++)
#pragma unroll
    for (int c = 0; c < 4; c++) ga[a][c] = 0.f;
  for (int t = 0; t < 64; t++) {
    float4 a = *(const float4*)(ms + t * 68 + gi0);
    float4 bb = *(const float4*)(ms + t * 68 + gj0);
    ga[0][0] = fmaf(a.x, bb.x, ga[0][0]); ga[0][1] = fmaf(a.x, bb.y, ga[0][1]);
    ga[0][2] = fmaf(a.x, bb.z, ga[0][2]); ga[0][3] = fmaf(a.x, bb.w, ga[0][3]);
    ga[1][0] = fmaf(a.y, bb.x, ga[1][0]); ga[1][1] = fmaf(a.y, bb.y, ga[1][1]);
    ga[1][2] = fmaf(a.y, bb.z, ga[1][2]); ga[1][3] = fmaf(a.y, bb.w, ga[1][3]);
    ga[2][0] = fmaf(a.z, bb.x, ga[2][0]); ga[2][1] = fmaf(a.z, bb.y, ga[2][1]);
    ga[2][2] = fmaf(a.z, bb.z, ga[2][2]); ga[2][3] = fmaf(a.z, bb.w, ga[2][3]);
    ga[3][0] = fmaf(a.w, bb.x, ga[3][0]); ga[3][1] = fmaf(a.w, bb.y, ga[3][1]);
    ga[3][2] = fmaf(a.w, bb.z, ga[3][2]); ga[3][3] = fmaf(a.w, bb.w, ga[3][3]);
  }
  u64* slot = CmAcc + (size_t)(bid & 3) * 4096;
#pragma unroll
  for (int ii = 0; ii < 4; ii++)
#pragma unroll
    for (int jj = 0; jj < 4; jj++)
      atomicAdd(slot + (gi0 + ii) * 64 + gj0 + jj, to_fx(ga[ii][jj]));
}

// ---------------- K3: correction + softmax2 -> M0; emit P0 ------------------
__launch_bounds__(256)
__global__ void k_correct(const float* __restrict__ Lbuf, const u64* __restrict__ CmAcc,
                          float* __restrict__ M0, u64* __restrict__ p0Acc) {
  __shared__ float ms[64 * 68];
  __shared__ float Cs[4096];
  __shared__ float cred[256];
  const int tid = threadIdx.x, bid = blockIdx.x;
  const int tg = tid >> 2, q = tid & 3;
  const int lane = tid & 63, w = tid >> 6;
  const int row = bid * 64 + tg;
  float l[16], m[16];
#pragma unroll
  for (int i = 0; i < 4; i++) {
    float4 lv = *(const float4*)(Lbuf + (size_t)row * NE + q * 16 + i * 4);
    l[i * 4 + 0] = lv.x; l[i * 4 + 1] = lv.y; l[i * 4 + 2] = lv.z; l[i * 4 + 3] = lv.w;
  }
  {
    float mx = -1e30f;
#pragma unroll
    for (int j = 0; j < 16; j++) mx = fmaxf(mx, l[j]);
    mx = warp4_max(mx);
    float ps = 0.f;
#pragma unroll
    for (int j = 0; j < 16; j++) { m[j] = expf(l[j] - mx); ps += m[j]; }
    ps = warp4_sum(ps);
    const float inv = 1.0f / ps;
#pragma unroll
    for (int j = 0; j < 16; j++) m[j] *= inv;
#pragma unroll
    for (int i = 0; i < 4; i++)
      *(float4*)(ms + tg * 68 + q * 16 + i * 4) =
          make_float4(m[i * 4], m[i * 4 + 1], m[i * 4 + 2], m[i * 4 + 3]);
  }
#pragma unroll 4
  for (int i = 0; i < 16; i++) {
    int idx = tid + i * 256;
    u64 s = CmAcc[idx] + CmAcc[4096 + idx] + CmAcc[8192 + idx] + CmAcc[12288 + idx];
    float v = (float)((double)s * (1.0 / 4294967296.0));
    int r = idx >> 6, c = idx & 63;
    Cs[idx] = (r == c) ? 0.f : v;
  }
  __syncthreads();
  {
    float g[16];
#pragma unroll
    for (int j = 0; j < 16; j++) g[j] = 0.f;
    for (int f = 0; f < 64; f++) {
      float mf = ms[tg * 68 + f];
#pragma unroll
      for (int i = 0; i < 4; i++) {
        float4 cv = *(const float4*)(Cs + f * 64 + q * 16 + i * 4);
        g[i * 4 + 0] = fmaf(mf, cv.x, g[i * 4 + 0]);
        g[i * 4 + 1] = fmaf(mf, cv.y, g[i * 4 + 1]);
        g[i * 4 + 2] = fmaf(mf, cv.z, g[i * 4 + 2]);
        g[i * 4 + 3] = fmaf(mf, cv.w, g[i * 4 + 3]);
      }
    }
    float dot = 0.f;
#pragma unroll
    for (int j = 0; j < 16; j++) { g[j] *= 4.f; dot += m[j] * g[j]; }
    dot = warp4_sum(dot);
    float mx = -1e30f;
#pragma unroll
    for (int j = 0; j < 16; j++) {
      l[j] = l[j] - LTAX * (m[j] * (g[j] - dot));
      mx = fmaxf(mx, l[j]);
    }
    mx = warp4_max(mx);
    float ps = 0.f;
#pragma unroll
    for (int j = 0; j < 16; j++) { m[j] = expf(l[j] - mx); ps += m[j]; }
    ps = warp4_sum(ps);
    const float inv = 1.0f / ps;
#pragma unroll
    for (int j = 0; j < 16; j++) m[j] *= inv;
#pragma unroll
    for (int i = 0; i < 4; i++)
      *(float4*)(M0 + (size_t)row * NE + q * 16 + i * 4) =
          make_float4(m[i * 4], m[i * 4 + 1], m[i * 4 + 2], m[i * 4 + 3]);
  }
  {
    float cs[16];
#pragma unroll
    for (int j = 0; j < 16; j++) cs[j] = m[j];
#pragma unroll
    for (int j = 0; j < 16; j++) {
      cs[j] += __shfl_xor(cs[j], 4);  cs[j] += __shfl_xor(cs[j], 8);
      cs[j] += __shfl_xor(cs[j], 16); cs[j] += __shfl_xor(cs[j], 32);
    }
    if ((lane >> 2) == 0) {
#pragma unroll
      for (int j = 0; j < 16; j++) cred[w * 64 + lane * 16 + j] = cs[j];
    }
    __syncthreads();
    if (tid < 64)
      atomicAdd(p0Acc + (size_t)(bid & 15) * 64 + tid,
                to_fx(cred[tid] + cred[64 + tid] + cred[128 + tid] + cred[192 + tid]));
  }
}

// ---------------- K4: one factored Sinkhorn iteration -----------------------
__launch_bounds__(256)
__global__ void k_sink(const float* __restrict__ M0, const u64* __restrict__ pin,
                       u64* __restrict__ pout) {
  __shared__ u64 pred[4][64];
  __shared__ float fac[64];
  __shared__ float cred[256];
  const int tid = threadIdx.x, bid = blockIdx.x;
  const int tg = tid >> 2, q = tid & 3;
  const int lane = tid & 63, w = tid >> 6;
  const int row = bid * 64 + tg;
  {
    const int grp = tid >> 6, e = tid & 63;
    pred[grp][e] = pin[grp * 64 + e] + pin[(grp + 4) * 64 + e] +
                   pin[(grp + 8) * 64 + e] + pin[(grp + 12) * 64 + e];
  }
  __syncthreads();
  if (tid < 64) {
    u64 s = pred[0][tid] + pred[1][tid] + pred[2][tid] + pred[3][tid];
    float P = (float)((double)s * (1.0 / 4294967296.0));
    fac[tid] = 256.0f / fmaxf(P, 1e-30f);     // V(e)
  }
  __syncthreads();
  float mv[16];
#pragma unroll
  for (int i = 0; i < 4; i++) {
    float4 v = *(const float4*)(M0 + (size_t)row * NE + q * 16 + i * 4);
    mv[i * 4 + 0] = v.x; mv[i * 4 + 1] = v.y; mv[i * 4 + 2] = v.z; mv[i * 4 + 3] = v.w;
  }
  float Q = 0.f;
#pragma unroll
  for (int j = 0; j < 16; j++) Q = fmaf(mv[j], fac[q * 16 + j], Q);
  Q = warp4_sum(Q);
  const float U = 1.0f / fmaxf(Q, 1e-30f);
  float cs[16];
#pragma unroll
  for (int j = 0; j < 16; j++) cs[j] = U * mv[j];
#pragma unroll
  for (int j = 0; j < 16; j++) {
    cs[j] += __shfl_xor(cs[j], 4);  cs[j] += __shfl_xor(cs[j], 8);
    cs[j] += __shfl_xor(cs[j], 16); cs[j] += __shfl_xor(cs[j], 32);
  }
  if ((lane >> 2) == 0) {
#pragma unroll
    for (int j = 0; j < 16; j++) cred[w * 64 + lane * 16 + j] = cs[j];
  }
  __syncthreads();
  if (tid < 64)
    atomicAdd(pout + (size_t)(bid & 15) * 64 + tid,
              to_fx(cred[tid] + cred[64 + tid] + cred[128 + tid] + cred[192 + tid]));
}

// ---------------- K5: final M10 + damping + hysteresis + topk ---------------
__launch_bounds__(256)
__global__ void k_final(const float* __restrict__ M0, const u64* __restrict__ pin,
                        const float* __restrict__ pp, const void* __restrict__ pmask,
                        float* __restrict__ out) {
  __shared__ u64 pred[4][64];
  __shared__ float fac[64];
  __shared__ int s_cnt[256];
  __shared__ int s_flag;
  const int tid = threadIdx.x, bid = blockIdx.x;
  const int tg = tid >> 2, q = tid & 3;
  const int lane = tid & 63;
  const int row = bid * 64 + tg;

  {
    uint4 v = ((const uint4*)pmask)[tid];
    int c = 0; u32 ww;
    ww = v.x; c += ((ww & 0xffu) != 0) + ((ww & 0xff00u) != 0) + ((ww & 0xff0000u) != 0) + ((ww & 0xff000000u) != 0);
    ww = v.y; c += ((ww & 0xffu) != 0) + ((ww & 0xff00u) != 0) + ((ww & 0xff0000u) != 0) + ((ww & 0xff000000u) != 0);
    ww = v.z; c += ((ww & 0xffu) != 0) + ((ww & 0xff00u) != 0) + ((ww & 0xff0000u) != 0) + ((ww & 0xff000000u) != 0);
    ww = v.w; c += ((ww & 0xffu) != 0) + ((ww & 0xff00u) != 0) + ((ww & 0xff0000u) != 0) + ((ww & 0xff000000u) != 0);
    s_cnt[tid] = c;
    __syncthreads();
    for (int s = 128; s; s >>= 1) { if (tid < s) s_cnt[tid] += s_cnt[tid + s]; __syncthreads(); }
    if (tid == 0) { int n = s_cnt[0]; s_flag = (n > 384) ? 0 : ((n > 192) ? 2 : 1); }
  }
  {
    const int grp = tid >> 6, e = tid & 63;
    pred[grp][e] = pin[grp * 64 + e] + pin[(grp + 4) * 64 + e] +
                   pin[(grp + 8) * 64 + e] + pin[(grp + 12) * 64 + e];
  }
  __syncthreads();
  if (tid < 64) {
    u64 s = pred[0][tid] + pred[1][tid] + pred[2][tid] + pred[3][tid];
    float P = (float)((double)s * (1.0 / 4294967296.0));
    fac[tid] = 256.0f / fmaxf(P, 1e-30f);     // V10
  }
  __syncthreads();

  float mv[16];
#pragma unroll
  for (int i = 0; i < 4; i++) {
    float4 v = *(const float4*)(M0 + (size_t)row * NE + q * 16 + i * 4);
    mv[i * 4 + 0] = v.x; mv[i * 4 + 1] = v.y; mv[i * 4 + 2] = v.z; mv[i * 4 + 3] = v.w;
  }
  float Q = 0.f;
#pragma unroll
  for (int j = 0; j < 16; j++) Q = fmaf(mv[j], fac[q * 16 + j], Q);
  Q = warp4_sum(Q);
  const float U = 1.0f / fmaxf(Q, 1e-30f);
  float m[16];
#pragma unroll
  for (int j = 0; j < 16; j++) m[j] = U * mv[j] * fac[q * 16 + j];   // M10 row

  const int flag = s_flag;
  float pv[16], mk[16];
#pragma unroll
  for (int i = 0; i < 4; i++) {
    float4 v = *(const float4*)(pp + (size_t)row * NE + q * 16 + i * 4);
    pv[i * 4 + 0] = v.x; pv[i * 4 + 1] = v.y; pv[i * 4 + 2] = v.z; pv[i * 4 + 3] = v.w;
  }
  if (flag == 0) {
    const u32* pb = (const u32*)pmask + row * 16 + q * 4;
#pragma unroll
    for (int i = 0; i < 4; i++) {
      u32 ww = pb[i];
      mk[i * 4 + 0] = (ww & 0xffu) ? 1.f : 0.f;
      mk[i * 4 + 1] = (ww & 0xff00u) ? 1.f : 0.f;
      mk[i * 4 + 2] = (ww & 0xff0000u) ? 1.f : 0.f;
      mk[i * 4 + 3] = (ww & 0xff000000u) ? 1.f : 0.f;
    }
  } else if (flag == 1) {
    const int* pb = (const int*)pmask + (size_t)row * NE + q * 16;
#pragma unroll
    for (int j = 0; j < 16; j++) mk[j] = pb[j] ? 1.f : 0.f;
  } else {
    const float* pb = (const float*)pmask + (size_t)row * NE + q * 16;
#pragma unroll
    for (int j = 0; j < 16; j++) mk[j] = (pb[j] != 0.f) ? 1.f : 0.f;
  }
  float msum = 0.f;
#pragma unroll
  for (int j = 0; j < 16; j++) msum += mk[j];
  msum = warp4_sum(msum);
  const float hscale = HYST / fmaxf(msum, 1.0f);
  float v[16];
  float s = 0.f;
#pragma unroll
  for (int j = 0; j < 16; j++) {
    float base = (1.f - ALPHA) * pv[j] + ALPHA * m[j];
    v[j] = (1.f - HYST) * base + hscale * mk[j];
    s += v[j];
  }
  s = warp4_sum(s);
  const float inv = 1.0f / fmaxf(s, 1e-12f);
#pragma unroll
  for (int j = 0; j < 16; j++) v[j] *= inv;

  float* mout = out;
  float* kout = out + (size_t)NT * NE;
#pragma unroll
  for (int i = 0; i < 4; i++)
    *(float4*)(mout + (size_t)row * NE + q * 16 + i * 4) =
        make_float4(v[i * 4], v[i * 4 + 1], v[i * 4 + 2], v[i * 4 + 3]);

  int cnt[16];
#pragma unroll
  for (int j = 0; j < 16; j++) cnt[j] = 0;
  const int base = lane & ~3;
#pragma unroll
  for (int oq = 0; oq < 4; oq++) {
#pragma unroll
    for (int j2 = 0; j2 < 16; j2++) {
      float ov = __shfl(v[j2], base + oq, 64);
      int oe = oq * 16 + j2;
#pragma unroll
      for (int j = 0; j < 16; j++) {
        int me = q * 16 + j;
        if (ov > v[j] || (ov == v[j] && oe < me)) cnt[j]++;
      }
    }
  }
#pragma unroll
  for (int i = 0; i < 4; i++)
    *(float4*)(kout + (size_t)row * NE + q * 16 + i * 4) =
        make_float4(cnt[i * 4] < TOPK ? 1.f : 0.f, cnt[i * 4 + 1] < TOPK ? 1.f : 0.f,
                    cnt[i * 4 + 2] < TOPK ? 1.f : 0.f, cnt[i * 4 + 3] < TOPK ? 1.f : 0.f);
}

extern "C" void kernel_launch(void* const* d_in, const int* in_sizes, int n_in,
                              void* d_out, int out_size, void* d_ws, size_t ws_size,
                              hipStream_t stream) {
  const float* x = (const float*)d_in[0];
  const float* W = (const float*)d_in[1];
  const float* b = (const float*)d_in[2];
  const float* pp = (const float*)d_in[3];
  const void* pmask = d_in[4];
  float* out = (float*)d_out;

  // pick split-K: 8 if Lpart (splitk*4MB) + rest fits in ws, else 4.
  // Deterministic (depends only on constant ws_size).
  const size_t fixed = 786432 /*Wpack*/ + 2 * 4194304 /*Lbuf,M0*/ + 212992 /*acc*/;
  int lg = (fixed + 8ull * NT * NE * 4 <= ws_size) ? 3 : 2;
  const int splitk = 1 << lg;

  unsigned char* wsb = (unsigned char*)d_ws;
  u16* Wpack = (u16*)(wsb);                          // 768 KB
  float* Lpart = (float*)(wsb + 786432);             // splitk * 4 MB
  size_t off = 786432 + (size_t)splitk * NT * NE * 4;
  float* Lbuf = (float*)(wsb + off);                 // 4 MB
  float* M0buf = (float*)(wsb + off + 4194304);      // 4 MB
  u64* CmAcc = (u64*)(wsb + off + 8388608);          // 128 KB
  u64* pAcc = (u64*)(wsb + off + 8519680);           // 80 KB

  k_init<<<168, 256, 0, stream>>>(W, Wpack, CmAcc);   // pack W + zero 26624 u64
  k_gemm<<<256 << lg, 256, 0, stream>>>(x, Wpack, Lpart, lg);
  k_post<<<256, 256, 0, stream>>>(Lpart, b, Lbuf, CmAcc, splitk);
  k_correct<<<256, 256, 0, stream>>>(Lbuf, CmAcc, M0buf, pAcc);
  for (int k = 1; k <= 9; k++)
    k_sink<<<256, 256, 0, stream>>>(M0buf, pAcc + (size_t)(k - 1) * 1024,
                                    pAcc + (size_t)k * 1024);
  k_final<<<256, 256, 0, stream>>>(M0buf, pAcc + (size_t)9 * 1024, pp, pmask, out);
}

// Round 17
// 180.062 us; speedup vs baseline: 1.0508x; 1.0364x over previous
//
#include <hip/hip_runtime.h>
#include <math.h>

#define NT 16384
#define DM 2048
#define NE 64
#define TOPK 8
#define LTAX 0.04f
#define HYST 0.1f
#define ALPHA 0.7f

typedef unsigned int u32;
typedef unsigned short u16;
typedef unsigned long long u64;
typedef __attribute__((ext_vector_type(8))) short bf16x8;
typedef __attribute__((ext_vector_type(4))) float f32x4;

__device__ __forceinline__ float warp4_sum(float v) {
  v += __shfl_xor(v, 1); v += __shfl_xor(v, 2); return v;
}
__device__ __forceinline__ float warp4_max(float v) {
  v = fmaxf(v, __shfl_xor(v, 1)); v = fmaxf(v, __shfl_xor(v, 2)); return v;
}
__device__ __forceinline__ u16 f2bf(float f) {   // RNE f32->bf16
  u32 u = __float_as_uint(f);
  return (u16)((u + 0x7fffu + ((u >> 16) & 1u)) >> 16);
}
__device__ __forceinline__ float bf2f(u16 h) { return __uint_as_float(((u32)h) << 16); }

__device__ __forceinline__ void split3(float a, short& h, short& m, short& l) {
  u16 hh = f2bf(a);  float r1 = a - bf2f(hh);     // exact (Sterbenz)
  u16 mm = f2bf(r1); float r2 = r1 - bf2f(mm);    // exact
  h = (short)hh; m = (short)mm; l = (short)f2bf(r2);
}

// fixed-point 2^32: exact-commutative integer atomics => deterministic
__device__ __forceinline__ u64 to_fx(float v) {
  return (u64)__double2ll_rn((double)v * 4294967296.0);
}

// ---------------- K0: fused W-split (row-major hi/mid/lo) + zero ------------
__global__ void k_init(const float* __restrict__ W, u16* __restrict__ Wh,
                       u16* __restrict__ Wm, u16* __restrict__ Wl,
                       u64* __restrict__ zp) {
  const int bid = blockIdx.x, tid = threadIdx.x;
  if (bid < 128) {
    int idx = (bid * 256 + tid) * 4;
    float4 v = *(const float4*)(W + idx);
    short h[4], m[4], l[4];
    split3(v.x, h[0], m[0], l[0]);
    split3(v.y, h[1], m[1], l[1]);
    split3(v.z, h[2], m[2], l[2]);
    split3(v.w, h[3], m[3], l[3]);
    *(ushort4*)(Wh + idx) = make_ushort4((u16)h[0], (u16)h[1], (u16)h[2], (u16)h[3]);
    *(ushort4*)(Wm + idx) = make_ushort4((u16)m[0], (u16)m[1], (u16)m[2], (u16)m[3]);
    *(ushort4*)(Wl + idx) = make_ushort4((u16)l[0], (u16)l[1], (u16)l[2], (u16)l[3]);
  } else {
    int i = (bid - 128) * 256 + tid;
    if (i < 26624) zp[i] = 0ull;
  }
}

// ---------------- K1: LDS MFMA GEMM, split-K=4, 4 blocks/CU -----------------
// R14's proven inner loop (LDS staging, 0 bank conflicts); grid 1024 with
// launch_bounds(256,4) doubles TLP vs R14 (latency was the limiter). f32
// partial stores (validated R15/R16). f64 flush every 8 chunks, fixed order.
__launch_bounds__(256, 4)
__global__ void k_gemm(const float* __restrict__ x, const u16* __restrict__ Whg,
                       const u16* __restrict__ Wmg, const u16* __restrict__ Wlg,
                       float* __restrict__ Lpart) {
  __shared__ __align__(16) u16 XS[30720];   // 6 arrays x 2 buf x [64][40]
  const int tid = threadIdx.x;
  const int bid = blockIdx.x;
  const int tile = bid >> 2, ks = bid & 3;
  const int row0 = tile * 64;
  const int k0 = ks * 512;
  const int lane = tid & 63, w = tid >> 6, l15 = lane & 15, l4 = lane >> 4;
  const int srow = tid >> 2, c8 = (tid & 3) * 8;
  const int stoff = srow * 40 + c8;

  f32x4 accA[4], accB[4];
  double accD[4][4];
#pragma unroll
  for (int eb = 0; eb < 4; eb++) {
    accA[eb] = (f32x4)0.f; accB[eb] = (f32x4)0.f;
#pragma unroll
    for (int r = 0; r < 4; r++) accD[eb][r] = 0.0;
  }

  float4 xq0, xq1;
  uint4 whv, wmv, wlv;
  const float* xrowp = x + (size_t)(row0 + srow) * DM + k0 + c8;
  const u16* whp = Whg + srow * DM + k0 + c8;
  const u16* wmp = Wmg + srow * DM + k0 + c8;
  const u16* wlp = Wlg + srow * DM + k0 + c8;

#define LOADCH(KC) { \
    xq0 = *(const float4*)(xrowp + (KC)); \
    xq1 = *(const float4*)(xrowp + (KC) + 4); \
    whv = *(const uint4*)(whp + (KC)); \
    wmv = *(const uint4*)(wmp + (KC)); \
    wlv = *(const uint4*)(wlp + (KC)); }

#define WRITECH(B) { \
    short ha[8], ma[8], la[8]; \
    split3(xq0.x, ha[0], ma[0], la[0]); \
    split3(xq0.y, ha[1], ma[1], la[1]); \
    split3(xq0.z, ha[2], ma[2], la[2]); \
    split3(xq0.w, ha[3], ma[3], la[3]); \
    split3(xq1.x, ha[4], ma[4], la[4]); \
    split3(xq1.y, ha[5], ma[5], la[5]); \
    split3(xq1.z, ha[6], ma[6], la[6]); \
    split3(xq1.w, ha[7], ma[7], la[7]); \
    bf16x8 xh8, xm8, xl8; \
    _Pragma("unroll") \
    for (int z = 0; z < 8; z++) { xh8[z] = ha[z]; xm8[z] = ma[z]; xl8[z] = la[z]; } \
    *(bf16x8*)(XS + 0     + (B) * 2560 + stoff) = xh8; \
    *(bf16x8*)(XS + 5120  + (B) * 2560 + stoff) = xm8; \
    *(bf16x8*)(XS + 10240 + (B) * 2560 + stoff) = xl8; \
    *(uint4*)(XS + 15360 + (B) * 2560 + stoff) = whv; \
    *(uint4*)(XS + 20480 + (B) * 2560 + stoff) = wmv; \
    *(uint4*)(XS + 25600 + (B) * 2560 + stoff) = wlv; }

#define COMPUTECH(B) { \
    const int ar = (w * 16 + l15) * 40 + l4 * 8; \
    bf16x8 ah = *(const bf16x8*)(XS + 0     + (B) * 2560 + ar); \
    bf16x8 am = *(const bf16x8*)(XS + 5120  + (B) * 2560 + ar); \
    bf16x8 al = *(const bf16x8*)(XS + 10240 + (B) * 2560 + ar); \
    _Pragma("unroll") \
    for (int eb = 0; eb < 4; eb++) { \
      const int br = (eb * 16 + l15) * 40 + l4 * 8; \
      bf16x8 bh = *(const bf16x8*)(XS + 15360 + (B) * 2560 + br); \
      bf16x8 bm = *(const bf16x8*)(XS + 20480 + (B) * 2560 + br); \
      bf16x8 bl = *(const bf16x8*)(XS + 25600 + (B) * 2560 + br); \
      accA[eb] = __builtin_amdgcn_mfma_f32_16x16x32_bf16(ah, bh, accA[eb], 0, 0, 0); \
      accB[eb] = __builtin_amdgcn_mfma_f32_16x16x32_bf16(ah, bm, accB[eb], 0, 0, 0); \
      accB[eb] = __builtin_amdgcn_mfma_f32_16x16x32_bf16(am, bh, accB[eb], 0, 0, 0); \
      accB[eb] = __builtin_amdgcn_mfma_f32_16x16x32_bf16(am, bm, accB[eb], 0, 0, 0); \
      accB[eb] = __builtin_amdgcn_mfma_f32_16x16x32_bf16(ah, bl, accB[eb], 0, 0, 0); \
      accB[eb] = __builtin_amdgcn_mfma_f32_16x16x32_bf16(al, bh, accB[eb], 0, 0, 0); \
    } }

  LOADCH(0);
  WRITECH(0);
  __syncthreads();
#pragma unroll 1
  for (int t = 0; t < 16; t++) {
    if (t < 15) LOADCH((t + 1) * 32);
    COMPUTECH(t & 1);
    if ((t & 7) == 7) {
#pragma unroll
      for (int eb = 0; eb < 4; eb++) {
#pragma unroll
        for (int r = 0; r < 4; r++)
          accD[eb][r] += (double)accA[eb][r] + (double)accB[eb][r];
        accA[eb] = (f32x4)0.f; accB[eb] = (f32x4)0.f;
      }
    }
    if (t < 15) WRITECH((t + 1) & 1);
    __syncthreads();
  }

  // C/D layout: col=lane&15 (expert), row=(lane>>4)*4+reg (token) [verified]
  float* outp = Lpart + (size_t)ks * NT * NE;
#pragma unroll
  for (int eb = 0; eb < 4; eb++)
#pragma unroll
    for (int r = 0; r < 4; r++) {
      int trow = w * 16 + l4 * 4 + r;
      outp[(size_t)(row0 + trow) * NE + eb * 16 + l15] = (float)accD[eb][r];
    }
}

// ---------------- K2: reduce 4 partials + center + softmax1 + gram ----------
__launch_bounds__(256)
__global__ void k_post(const float* __restrict__ Lpart, const float* __restrict__ b,
                       float* __restrict__ Lbuf, u64* __restrict__ CmAcc) {
  __shared__ float ms[64 * 68];
  const int tid = threadIdx.x, bid = blockIdx.x;
  const int tg = tid >> 2, q = tid & 3;
  const int row = bid * 64 + tg;
  float l[16], m[16];
  {
    double acc[16];
#pragma unroll
    for (int j = 0; j < 16; j++) acc[j] = 0.0;
#pragma unroll 1
    for (int ks = 0; ks < 4; ks++) {
      const float* p = Lpart + (size_t)ks * NT * NE + (size_t)row * NE + q * 16;
#pragma unroll
      for (int i = 0; i < 4; i++) {
        float4 v = *(const float4*)(p + i * 4);
        acc[i * 4 + 0] += (double)v.x; acc[i * 4 + 1] += (double)v.y;
        acc[i * 4 + 2] += (double)v.z; acc[i * 4 + 3] += (double)v.w;
      }
    }
#pragma unroll
    for (int i = 0; i < 4; i++) {
      float4 bv = *(const float4*)(b + q * 16 + i * 4);
      l[i * 4 + 0] = (float)acc[i * 4 + 0] + bv.x;
      l[i * 4 + 1] = (float)acc[i * 4 + 1] + bv.y;
      l[i * 4 + 2] = (float)acc[i * 4 + 2] + bv.z;
      l[i * 4 + 3] = (float)acc[i * 4 + 3] + bv.w;
    }
    float s = 0.f;
#pragma unroll
    for (int j = 0; j < 16; j++) s += l[j];
    s = warp4_sum(s);
    const float mean = s * (1.0f / 64.0f);
    float mx = -1e30f;
#pragma unroll
    for (int j = 0; j < 16; j++) { l[j] -= mean; mx = fmaxf(mx, l[j]); }
    mx = warp4_max(mx);
#pragma unroll
    for (int i = 0; i < 4; i++)
      *(float4*)(Lbuf + (size_t)row * NE + q * 16 + i * 4) =
          make_float4(l[i * 4], l[i * 4 + 1], l[i * 4 + 2], l[i * 4 + 3]);
    float ps = 0.f;
#pragma unroll
    for (int j = 0; j < 16; j++) { m[j] = expf(l[j] - mx); ps += m[j]; }
    ps = warp4_sum(ps);
    const float inv = 1.0f / ps;
#pragma unroll
    for (int j = 0; j < 16; j++) m[j] *= inv;
#pragma unroll
    for (int i = 0; i < 4; i++)
      *(float4*)(ms + tg * 68 + q * 16 + i * 4) =
          make_float4(m[i * 4], m[i * 4 + 1], m[i * 4 + 2], m[i * 4 + 3]);
  }
  __syncthreads();
  // gram partial -> slotted fx atomics (slot = bid & 3)
  const int gi0 = (tid >> 4) * 4;
  const int gj0 = (tid & 15) * 4;
  float ga[4][4];
#pragma unroll
  for (int a = 0; a < 4; a++)
#pragma unroll
    for (int c = 0; c < 4; c++) ga[a][c] = 0.f;
  for (int t = 0; t < 64; t++) {
    float4 a = *(const float4*)(ms + t * 68 + gi0);
    float4 bb = *(const float4*)(ms + t * 68 + gj0);
    ga[0][0] = fmaf(a.x, bb.x, ga[0][0]); ga[0][1] = fmaf(a.x, bb.y, ga[0][1]);
    ga[0][2] = fmaf(a.x, bb.z, ga[0][2]); ga[0][3] = fmaf(a.x, bb.w, ga[0][3]);
    ga[1][0] = fmaf(a.y, bb.x, ga[1][0]); ga[1][1] = fmaf(a.y, bb.y, ga[1][1]);
    ga[1][2] = fmaf(a.y, bb.z, ga[1][2]); ga[1][3] = fmaf(a.y, bb.w, ga[1][3]);
    ga[2][0] = fmaf(a.z, bb.x, ga[2][0]); ga[2][1] = fmaf(a.z, bb.y, ga[2][1]);
    ga[2][2] = fmaf(a.z, bb.z, ga[2][2]); ga[2][3] = fmaf(a.z, bb.w, ga[2][3]);
    ga[3][0] = fmaf(a.w, bb.x, ga[3][0]); ga[3][1] = fmaf(a.w, bb.y, ga[3][1]);
    ga[3][2] = fmaf(a.w, bb.z, ga[3][2]); ga[3][3] = fmaf(a.w, bb.w, ga[3][3]);
  }
  u64* slot = CmAcc + (size_t)(bid & 3) * 4096;
#pragma unroll
  for (int ii = 0; ii < 4; ii++)
#pragma unroll
    for (int jj = 0; jj < 4; jj++)
      atomicAdd(slot + (gi0 + ii) * 64 + gj0 + jj, to_fx(ga[ii][jj]));
}

// ---------------- K3: correction + softmax2 -> M0; emit P0 ------------------
__launch_bounds__(256)
__global__ void k_correct(const float* __restrict__ Lbuf, const u64* __restrict__ CmAcc,
                          float* __restrict__ M0, u64* __restrict__ p0Acc) {
  __shared__ float ms[64 * 68];
  __shared__ float Cs[4096];
  __shared__ float cred[256];
  const int tid = threadIdx.x, bid = blockIdx.x;
  const int tg = tid >> 2, q = tid & 3;
  const int lane = tid & 63, w = tid >> 6;
  const int row = bid * 64 + tg;
  float l[16], m[16];
#pragma unroll
  for (int i = 0; i < 4; i++) {
    float4 lv = *(const float4*)(Lbuf + (size_t)row * NE + q * 16 + i * 4);
    l[i * 4 + 0] = lv.x; l[i * 4 + 1] = lv.y; l[i * 4 + 2] = lv.z; l[i * 4 + 3] = lv.w;
  }
  {
    float mx = -1e30f;
#pragma unroll
    for (int j = 0; j < 16; j++) mx = fmaxf(mx, l[j]);
    mx = warp4_max(mx);
    float ps = 0.f;
#pragma unroll
    for (int j = 0; j < 16; j++) { m[j] = expf(l[j] - mx); ps += m[j]; }
    ps = warp4_sum(ps);
    const float inv = 1.0f / ps;
#pragma unroll
    for (int j = 0; j < 16; j++) m[j] *= inv;
#pragma unroll
    for (int i = 0; i < 4; i++)
      *(float4*)(ms + tg * 68 + q * 16 + i * 4) =
          make_float4(m[i * 4], m[i * 4 + 1], m[i * 4 + 2], m[i * 4 + 3]);
  }
#pragma unroll 4
  for (int i = 0; i < 16; i++) {
    int idx = tid + i * 256;
    u64 s = CmAcc[idx] + CmAcc[4096 + idx] + CmAcc[8192 + idx] + CmAcc[12288 + idx];
    float v = (float)((double)s * (1.0 / 4294967296.0));
    int r = idx >> 6, c = idx & 63;
    Cs[idx] = (r == c) ? 0.f : v;
  }
  __syncthreads();
  {
    float g[16];
#pragma unroll
    for (int j = 0; j < 16; j++) g[j] = 0.f;
    for (int f = 0; f < 64; f++) {
      float mf = ms[tg * 68 + f];
#pragma unroll
      for (int i = 0; i < 4; i++) {
        float4 cv = *(const float4*)(Cs + f * 64 + q * 16 + i * 4);
        g[i * 4 + 0] = fmaf(mf, cv.x, g[i * 4 + 0]);
        g[i * 4 + 1] = fmaf(mf, cv.y, g[i * 4 + 1]);
        g[i * 4 + 2] = fmaf(mf, cv.z, g[i * 4 + 2]);
        g[i * 4 + 3] = fmaf(mf, cv.w, g[i * 4 + 3]);
      }
    }
    float dot = 0.f;
#pragma unroll
    for (int j = 0; j < 16; j++) { g[j] *= 4.f; dot += m[j] * g[j]; }
    dot = warp4_sum(dot);
    float mx = -1e30f;
#pragma unroll
    for (int j = 0; j < 16; j++) {
      l[j] = l[j] - LTAX * (m[j] * (g[j] - dot));
      mx = fmaxf(mx, l[j]);
    }
    mx = warp4_max(mx);
    float ps = 0.f;
#pragma unroll
    for (int j = 0; j < 16; j++) { m[j] = expf(l[j] - mx); ps += m[j]; }
    ps = warp4_sum(ps);
    const float inv = 1.0f / ps;
#pragma unroll
    for (int j = 0; j < 16; j++) m[j] *= inv;
#pragma unroll
    for (int i = 0; i < 4; i++)
      *(float4*)(M0 + (size_t)row * NE + q * 16 + i * 4) =
          make_float4(m[i * 4], m[i * 4 + 1], m[i * 4 + 2], m[i * 4 + 3]);
  }
  {
    float cs[16];
#pragma unroll
    for (int j = 0; j < 16; j++) cs[j] = m[j];
#pragma unroll
    for (int j = 0; j < 16; j++) {
      cs[j] += __shfl_xor(cs[j], 4);  cs[j] += __shfl_xor(cs[j], 8);
      cs[j] += __shfl_xor(cs[j], 16); cs[j] += __shfl_xor(cs[j], 32);
    }
    if ((lane >> 2) == 0) {
#pragma unroll
      for (int j = 0; j < 16; j++) cred[w * 64 + lane * 16 + j] = cs[j];
    }
    __syncthreads();
    if (tid < 64)
      atomicAdd(p0Acc + (size_t)(bid & 15) * 64 + tid,
                to_fx(cred[tid] + cred[64 + tid] + cred[128 + tid] + cred[192 + tid]));
  }
}

// ---------------- K4: one factored Sinkhorn iteration -----------------------
__launch_bounds__(256)
__global__ void k_sink(const float* __restrict__ M0, const u64* __restrict__ pin,
                       u64* __restrict__ pout) {
  __shared__ u64 pred[4][64];
  __shared__ float fac[64];
  __shared__ float cred[256];
  const int tid = threadIdx.x, bid = blockIdx.x;
  const int tg = tid >> 2, q = tid & 3;
  const int lane = tid & 63, w = tid >> 6;
  const int row = bid * 64 + tg;
  {
    const int grp = tid >> 6, e = tid & 63;
    pred[grp][e] = pin[grp * 64 + e] + pin[(grp + 4) * 64 + e] +
                   pin[(grp + 8) * 64 + e] + pin[(grp + 12) * 64 + e];
  }
  __syncthreads();
  if (tid < 64) {
    u64 s = pred[0][tid] + pred[1][tid] + pred[2][tid] + pred[3][tid];
    float P = (float)((double)s * (1.0 / 4294967296.0));
    fac[tid] = 256.0f / fmaxf(P, 1e-30f);     // V(e)
  }
  __syncthreads();
  float mv[16];
#pragma unroll
  for (int i = 0; i < 4; i++) {
    float4 v = *(const float4*)(M0 + (size_t)row * NE + q * 16 + i * 4);
    mv[i * 4 + 0] = v.x; mv[i * 4 + 1] = v.y; mv[i * 4 + 2] = v.z; mv[i * 4 + 3] = v.w;
  }
  float Q = 0.f;
#pragma unroll
  for (int j = 0; j < 16; j++) Q = fmaf(mv[j], fac[q * 16 + j], Q);
  Q = warp4_sum(Q);
  const float U = 1.0f / fmaxf(Q, 1e-30f);
  float cs[16];
#pragma unroll
  for (int j = 0; j < 16; j++) cs[j] = U * mv[j];
#pragma unroll
  for (int j = 0; j < 16; j++) {
    cs[j] += __shfl_xor(cs[j], 4);  cs[j] += __shfl_xor(cs[j], 8);
    cs[j] += __shfl_xor(cs[j], 16); cs[j] += __shfl_xor(cs[j], 32);
  }
  if ((lane >> 2) == 0) {
#pragma unroll
    for (int j = 0; j < 16; j++) cred[w * 64 + lane * 16 + j] = cs[j];
  }
  __syncthreads();
  if (tid < 64)
    atomicAdd(pout + (size_t)(bid & 15) * 64 + tid,
              to_fx(cred[tid] + cred[64 + tid] + cred[128 + tid] + cred[192 + tid]));
}

// ---------------- K5: final M10 + damping + hysteresis + topk ---------------
__launch_bounds__(256)
__global__ void k_final(const float* __restrict__ M0, const u64* __restrict__ pin,
                        const float* __restrict__ pp, const void* __restrict__ pmask,
                        float* __restrict__ out) {
  __shared__ u64 pred[4][64];
  __shared__ float fac[64];
  __shared__ int s_cnt[256];
  __shared__ int s_flag;
  const int tid = threadIdx.x, bid = blockIdx.x;
  const int tg = tid >> 2, q = tid & 3;
  const int lane = tid & 63;
  const int row = bid * 64 + tg;

  {
    uint4 v = ((const uint4*)pmask)[tid];
    int c = 0; u32 ww;
    ww = v.x; c += ((ww & 0xffu) != 0) + ((ww & 0xff00u) != 0) + ((ww & 0xff0000u) != 0) + ((ww & 0xff000000u) != 0);
    ww = v.y; c += ((ww & 0xffu) != 0) + ((ww & 0xff00u) != 0) + ((ww & 0xff0000u) != 0) + ((ww & 0xff000000u) != 0);
    ww = v.z; c += ((ww & 0xffu) != 0) + ((ww & 0xff00u) != 0) + ((ww & 0xff0000u) != 0) + ((ww & 0xff000000u) != 0);
    ww = v.w; c += ((ww & 0xffu) != 0) + ((ww & 0xff00u) != 0) + ((ww & 0xff0000u) != 0) + ((ww & 0xff000000u) != 0);
    s_cnt[tid] = c;
    __syncthreads();
    for (int s = 128; s; s >>= 1) { if (tid < s) s_cnt[tid] += s_cnt[tid + s]; __syncthreads(); }
    if (tid == 0) { int n = s_cnt[0]; s_flag = (n > 384) ? 0 : ((n > 192) ? 2 : 1); }
  }
  {
    const int grp = tid >> 6, e = tid & 63;
    pred[grp][e] = pin[grp * 64 + e] + pin[(grp + 4) * 64 + e] +
                   pin[(grp + 8) * 64 + e] + pin[(grp + 12) * 64 + e];
  }
  __syncthreads();
  if (tid < 64) {
    u64 s = pred[0][tid] + pred[1][tid] + pred[2][tid] + pred[3][tid];
    float P = (float)((double)s * (1.0 / 4294967296.0));
    fac[tid] = 256.0f / fmaxf(P, 1e-30f);     // V10
  }
  __syncthreads();

  float mv[16];
#pragma unroll
  for (int i = 0; i < 4; i++) {
    float4 v = *(const float4*)(M0 + (size_t)row * NE + q * 16 + i * 4);
    mv[i * 4 + 0] = v.x; mv[i * 4 + 1] = v.y; mv[i * 4 + 2] = v.z; mv[i * 4 + 3] = v.w;
  }
  float Q = 0.f;
#pragma unroll
  for (int j = 0; j < 16; j++) Q = fmaf(mv[j], fac[q * 16 + j], Q);
  Q = warp4_sum(Q);
  const float U = 1.0f / fmaxf(Q, 1e-30f);
  float m[16];
#pragma unroll
  for (int j = 0; j < 16; j++) m[j] = U * mv[j] * fac[q * 16 + j];   // M10 row

  const int flag = s_flag;
  float pv[16], mk[16];
#pragma unroll
  for (int i = 0; i < 4; i++) {
    float4 v = *(const float4*)(pp + (size_t)row * NE + q * 16 + i * 4);
    pv[i * 4 + 0] = v.x; pv[i * 4 + 1] = v.y; pv[i * 4 + 2] = v.z; pv[i * 4 + 3] = v.w;
  }
  if (flag == 0) {
    const u32* pb = (const u32*)pmask + row * 16 + q * 4;
#pragma unroll
    for (int i = 0; i < 4; i++) {
      u32 ww = pb[i];
      mk[i * 4 + 0] = (ww & 0xffu) ? 1.f : 0.f;
      mk[i * 4 + 1] = (ww & 0xff00u) ? 1.f : 0.f;
      mk[i * 4 + 2] = (ww & 0xff0000u) ? 1.f : 0.f;
      mk[i * 4 + 3] = (ww & 0xff000000u) ? 1.f : 0.f;
    }
  } else if (flag == 1) {
    const int* pb = (const int*)pmask + (size_t)row * NE + q * 16;
#pragma unroll
    for (int j = 0; j < 16; j++) mk[j] = pb[j] ? 1.f : 0.f;
  } else {
    const float* pb = (const float*)pmask + (size_t)row * NE + q * 16;
#pragma unroll
    for (int j = 0; j < 16; j++) mk[j] = (pb[j] != 0.f) ? 1.f : 0.f;
  }
  float msum = 0.f;
#pragma unroll
  for (int j = 0; j < 16; j++) msum += mk[j];
  msum = warp4_sum(msum);
  const float hscale = HYST / fmaxf(msum, 1.0f);
  float v[16];
  float s = 0.f;
#pragma unroll
  for (int j = 0; j < 16; j++) {
    float base = (1.f - ALPHA) * pv[j] + ALPHA * m[j];
    v[j] = (1.f - HYST) * base + hscale * mk[j];
    s += v[j];
  }
  s = warp4_sum(s);
  const float inv = 1.0f / fmaxf(s, 1e-12f);
#pragma unroll
  for (int j = 0; j < 16; j++) v[j] *= inv;

  float* mout = out;
  float* kout = out + (size_t)NT * NE;
#pragma unroll
  for (int i = 0; i < 4; i++)
    *(float4*)(mout + (size_t)row * NE + q * 16 + i * 4) =
        make_float4(v[i * 4], v[i * 4 + 1], v[i * 4 + 2], v[i * 4 + 3]);

  int cnt[16];
#pragma unroll
  for (int j = 0; j < 16; j++) cnt[j] = 0;
  const int base = lane & ~3;
#pragma unroll
  for (int oq = 0; oq < 4; oq++) {
#pragma unroll
    for (int j2 = 0; j2 < 16; j2++) {
      float ov = __shfl(v[j2], base + oq, 64);
      int oe = oq * 16 + j2;
#pragma unroll
      for (int j = 0; j < 16; j++) {
        int me = q * 16 + j;
        if (ov > v[j] || (ov == v[j] && oe < me)) cnt[j]++;
      }
    }
  }
#pragma unroll
  for (int i = 0; i < 4; i++)
    *(float4*)(kout + (size_t)row * NE + q * 16 + i * 4) =
        make_float4(cnt[i * 4] < TOPK ? 1.f : 0.f, cnt[i * 4 + 1] < TOPK ? 1.f : 0.f,
                    cnt[i * 4 + 2] < TOPK ? 1.f : 0.f, cnt[i * 4 + 3] < TOPK ? 1.f : 0.f);
}

extern "C" void kernel_launch(void* const* d_in, const int* in_sizes, int n_in,
                              void* d_out, int out_size, void* d_ws, size_t ws_size,
                              hipStream_t stream) {
  const float* x = (const float*)d_in[0];
  const float* W = (const float*)d_in[1];
  const float* b = (const float*)d_in[2];
  const float* pp = (const float*)d_in[3];
  const void* pmask = d_in[4];
  float* out = (float*)d_out;

  unsigned char* wsb = (unsigned char*)d_ws;
  u16* Wh = (u16*)(wsb);                          // 256 KB
  u16* Wm = (u16*)(wsb + 262144);                 // 256 KB
  u16* Wl = (u16*)(wsb + 524288);                 // 256 KB
  float* Lpart = (float*)(wsb + 786432);          // 4 slices * 4 MB = 16 MB
  float* Lbuf = (float*)(wsb + 17563648);         // 4 MB
  float* M0buf = (float*)(wsb + 21757952);        // 4 MB
  u64* CmAcc = (u64*)(wsb + 25952256);            // 128 KB
  u64* pAcc = (u64*)(wsb + 26083328);             // 80 KB

  k_init<<<232, 256, 0, stream>>>(W, Wh, Wm, Wl, CmAcc);   // split W + zero acc
  k_gemm<<<1024, 256, 0, stream>>>(x, Wh, Wm, Wl, Lpart);
  k_post<<<256, 256, 0, stream>>>(Lpart, b, Lbuf, CmAcc);
  k_correct<<<256, 256, 0, stream>>>(Lbuf, CmAcc, M0buf, pAcc);
  for (int k = 1; k <= 9; k++)
    k_sink<<<256, 256, 0, stream>>>(M0buf, pAcc + (size_t)(k - 1) * 1024,
                                    pAcc + (size_t)k * 1024);
  k_final<<<256, 256, 0, stream>>>(M0buf, pAcc + (size_t)9 * 1024, pp, pmask, out);
}

// Round 18
// 176.435 us; speedup vs baseline: 1.0724x; 1.0206x over previous
//
#include <hip/hip_runtime.h>
#include <math.h>

#define NT 16384
#define DM 2048
#define NE 64
#define TOPK 8
#define LTAX 0.04f
#define HYST 0.1f
#define ALPHA 0.7f

typedef unsigned int u32;
typedef unsigned short u16;
typedef unsigned long long u64;
typedef __attribute__((ext_vector_type(8))) short bf16x8;
typedef __attribute__((ext_vector_type(4))) float f32x4;

__device__ __forceinline__ float warp4_sum(float v) {
  v += __shfl_xor(v, 1); v += __shfl_xor(v, 2); return v;
}
__device__ __forceinline__ float warp4_max(float v) {
  v = fmaxf(v, __shfl_xor(v, 1)); v = fmaxf(v, __shfl_xor(v, 2)); return v;
}
__device__ __forceinline__ u16 f2bf(float f) {   // RNE f32->bf16
  u32 u = __float_as_uint(f);
  return (u16)((u + 0x7fffu + ((u >> 16) & 1u)) >> 16);
}
__device__ __forceinline__ float bf2f(u16 h) { return __uint_as_float(((u32)h) << 16); }

__device__ __forceinline__ void split3(float a, short& h, short& m, short& l) {
  u16 hh = f2bf(a);  float r1 = a - bf2f(hh);     // exact (Sterbenz)
  u16 mm = f2bf(r1); float r2 = r1 - bf2f(mm);    // exact
  h = (short)hh; m = (short)mm; l = (short)f2bf(r2);
}

// fixed-point 2^32: exact-commutative integer atomics => deterministic
__device__ __forceinline__ u64 to_fx(float v) {
  return (u64)__double2ll_rn((double)v * 4294967296.0);
}

// ---------------- K0: fused W-split (row-major hi/mid/lo) + zero ------------
__global__ void k_init(const float* __restrict__ W, u16* __restrict__ Wh,
                       u16* __restrict__ Wm, u16* __restrict__ Wl,
                       u64* __restrict__ zp) {
  const int bid = blockIdx.x, tid = threadIdx.x;
  if (bid < 128) {
    int idx = (bid * 256 + tid) * 4;
    float4 v = *(const float4*)(W + idx);
    short h[4], m[4], l[4];
    split3(v.x, h[0], m[0], l[0]);
    split3(v.y, h[1], m[1], l[1]);
    split3(v.z, h[2], m[2], l[2]);
    split3(v.w, h[3], m[3], l[3]);
    *(ushort4*)(Wh + idx) = make_ushort4((u16)h[0], (u16)h[1], (u16)h[2], (u16)h[3]);
    *(ushort4*)(Wm + idx) = make_ushort4((u16)m[0], (u16)m[1], (u16)m[2], (u16)m[3]);
    *(ushort4*)(Wl + idx) = make_ushort4((u16)l[0], (u16)l[1], (u16)l[2], (u16)l[3]);
  } else {
    int i = (bid - 128) * 256 + tid;
    if (i < 26624) zp[i] = 0ull;
  }
}

// ---------------- K1: LDS MFMA GEMM, split-K=8, single-buffer, 5 blk/CU -----
// 2048 blocks, 30.7KB LDS each -> 5 resident/CU (20 waves/CU). Inter-block
// TLP hides the per-chunk barrier drains that stalled the 2-buffer variant.
// 8 chunks/slice, one f64 flush (bit-identical accumulation order to R16's
// passed split-K=8 path).
__launch_bounds__(256, 5)
__global__ void k_gemm(const float* __restrict__ x, const u16* __restrict__ Whg,
                       const u16* __restrict__ Wmg, const u16* __restrict__ Wlg,
                       float* __restrict__ Lpart) {
  __shared__ __align__(16) u16 XS[15360];   // 6 arrays x [64][40] u16
  const int tid = threadIdx.x;
  const int bid = blockIdx.x;
  const int tile = bid >> 3, ks = bid & 7;
  const int row0 = tile * 64;
  const int k0 = ks * 256;
  const int lane = tid & 63, w = tid >> 6, l15 = lane & 15, l4 = lane >> 4;
  const int srow = tid >> 2, c8 = (tid & 3) * 8;
  const int stoff = srow * 40 + c8;

  f32x4 accA[4], accB[4];
#pragma unroll
  for (int eb = 0; eb < 4; eb++) { accA[eb] = (f32x4)0.f; accB[eb] = (f32x4)0.f; }

  float4 xq0, xq1;
  uint4 whv, wmv, wlv;
  const float* xrowp = x + (size_t)(row0 + srow) * DM + k0 + c8;
  const u16* whp = Whg + srow * DM + k0 + c8;
  const u16* wmp = Wmg + srow * DM + k0 + c8;
  const u16* wlp = Wlg + srow * DM + k0 + c8;

#define LOADCH(KC) { \
    xq0 = *(const float4*)(xrowp + (KC)); \
    xq1 = *(const float4*)(xrowp + (KC) + 4); \
    whv = *(const uint4*)(whp + (KC)); \
    wmv = *(const uint4*)(wmp + (KC)); \
    wlv = *(const uint4*)(wlp + (KC)); }

#define WRITECH() { \
    short ha[8], ma[8], la[8]; \
    split3(xq0.x, ha[0], ma[0], la[0]); \
    split3(xq0.y, ha[1], ma[1], la[1]); \
    split3(xq0.z, ha[2], ma[2], la[2]); \
    split3(xq0.w, ha[3], ma[3], la[3]); \
    split3(xq1.x, ha[4], ma[4], la[4]); \
    split3(xq1.y, ha[5], ma[5], la[5]); \
    split3(xq1.z, ha[6], ma[6], la[6]); \
    split3(xq1.w, ha[7], ma[7], la[7]); \
    bf16x8 xh8, xm8, xl8; \
    _Pragma("unroll") \
    for (int z = 0; z < 8; z++) { xh8[z] = ha[z]; xm8[z] = ma[z]; xl8[z] = la[z]; } \
    *(bf16x8*)(XS + 0     + stoff) = xh8; \
    *(bf16x8*)(XS + 2560  + stoff) = xm8; \
    *(bf16x8*)(XS + 5120  + stoff) = xl8; \
    *(uint4*)(XS + 7680  + stoff) = whv; \
    *(uint4*)(XS + 10240 + stoff) = wmv; \
    *(uint4*)(XS + 12800 + stoff) = wlv; }

#define COMPUTECH() { \
    const int ar = (w * 16 + l15) * 40 + l4 * 8; \
    bf16x8 ah = *(const bf16x8*)(XS + 0    + ar); \
    bf16x8 am = *(const bf16x8*)(XS + 2560 + ar); \
    bf16x8 al = *(const bf16x8*)(XS + 5120 + ar); \
    _Pragma("unroll") \
    for (int eb = 0; eb < 4; eb++) { \
      const int br = (eb * 16 + l15) * 40 + l4 * 8; \
      bf16x8 bh = *(const bf16x8*)(XS + 7680  + br); \
      bf16x8 bm = *(const bf16x8*)(XS + 10240 + br); \
      bf16x8 bl = *(const bf16x8*)(XS + 12800 + br); \
      accA[eb] = __builtin_amdgcn_mfma_f32_16x16x32_bf16(ah, bh, accA[eb], 0, 0, 0); \
      accB[eb] = __builtin_amdgcn_mfma_f32_16x16x32_bf16(ah, bm, accB[eb], 0, 0, 0); \
      accB[eb] = __builtin_amdgcn_mfma_f32_16x16x32_bf16(am, bh, accB[eb], 0, 0, 0); \
      accB[eb] = __builtin_amdgcn_mfma_f32_16x16x32_bf16(am, bm, accB[eb], 0, 0, 0); \
      accB[eb] = __builtin_amdgcn_mfma_f32_16x16x32_bf16(ah, bl, accB[eb], 0, 0, 0); \
      accB[eb] = __builtin_amdgcn_mfma_f32_16x16x32_bf16(al, bh, accB[eb], 0, 0, 0); \
    } }

#pragma unroll 1
  for (int t = 0; t < 8; t++) {
    LOADCH(t * 32);
    __syncthreads();          // previous chunk's compute done before overwrite
    WRITECH();
    __syncthreads();
    COMPUTECH();
  }

  // single f64 flush (K=256 slice, same as R16's validated split-K=8 path)
  // C/D layout: col=lane&15 (expert), row=(lane>>4)*4+reg (token) [verified]
  float* outp = Lpart + (size_t)ks * NT * NE;
#pragma unroll
  for (int eb = 0; eb < 4; eb++)
#pragma unroll
    for (int r = 0; r < 4; r++) {
      int trow = w * 16 + l4 * 4 + r;
      outp[(size_t)(row0 + trow) * NE + eb * 16 + l15] =
          (float)((double)accA[eb][r] + (double)accB[eb][r]);
    }
}

// ---------------- K2: reduce 8 partials + center + softmax1 + gram ----------
__launch_bounds__(256)
__global__ void k_post(const float* __restrict__ Lpart, const float* __restrict__ b,
                       float* __restrict__ Lbuf, u64* __restrict__ CmAcc) {
  __shared__ float ms[64 * 68];
  const int tid = threadIdx.x, bid = blockIdx.x;
  const int tg = tid >> 2, q = tid & 3;
  const int row = bid * 64 + tg;
  float l[16], m[16];
  {
    double acc[16];
#pragma unroll
    for (int j = 0; j < 16; j++) acc[j] = 0.0;
#pragma unroll 1
    for (int ks = 0; ks < 8; ks++) {
      const float* p = Lpart + (size_t)ks * NT * NE + (size_t)row * NE + q * 16;
#pragma unroll
      for (int i = 0; i < 4; i++) {
        float4 v = *(const float4*)(p + i * 4);
        acc[i * 4 + 0] += (double)v.x; acc[i * 4 + 1] += (double)v.y;
        acc[i * 4 + 2] += (double)v.z; acc[i * 4 + 3] += (double)v.w;
      }
    }
#pragma unroll
    for (int i = 0; i < 4; i++) {
      float4 bv = *(const float4*)(b + q * 16 + i * 4);
      l[i * 4 + 0] = (float)acc[i * 4 + 0] + bv.x;
      l[i * 4 + 1] = (float)acc[i * 4 + 1] + bv.y;
      l[i * 4 + 2] = (float)acc[i * 4 + 2] + bv.z;
      l[i * 4 + 3] = (float)acc[i * 4 + 3] + bv.w;
    }
    float s = 0.f;
#pragma unroll
    for (int j = 0; j < 16; j++) s += l[j];
    s = warp4_sum(s);
    const float mean = s * (1.0f / 64.0f);
    float mx = -1e30f;
#pragma unroll
    for (int j = 0; j < 16; j++) { l[j] -= mean; mx = fmaxf(mx, l[j]); }
    mx = warp4_max(mx);
#pragma unroll
    for (int i = 0; i < 4; i++)
      *(float4*)(Lbuf + (size_t)row * NE + q * 16 + i * 4) =
          make_float4(l[i * 4], l[i * 4 + 1], l[i * 4 + 2], l[i * 4 + 3]);
    float ps = 0.f;
#pragma unroll
    for (int j = 0; j < 16; j++) { m[j] = expf(l[j] - mx); ps += m[j]; }
    ps = warp4_sum(ps);
    const float inv = 1.0f / ps;
#pragma unroll
    for (int j = 0; j < 16; j++) m[j] *= inv;
#pragma unroll
    for (int i = 0; i < 4; i++)
      *(float4*)(ms + tg * 68 + q * 16 + i * 4) =
          make_float4(m[i * 4], m[i * 4 + 1], m[i * 4 + 2], m[i * 4 + 3]);
  }
  __syncthreads();
  // gram partial -> slotted fx atomics (slot = bid & 3)
  const int gi0 = (tid >> 4) * 4;
  const int gj0 = (tid & 15) * 4;
  float ga[4][4];
#pragma unroll
  for (int a = 0; a < 4; a++)
#pragma unroll
    for (int c = 0; c < 4; c++) ga[a][c] = 0.f;
  for (int t = 0; t < 64; t++) {
    float4 a = *(const float4*)(ms + t * 68 + gi0);
    float4 bb = *(const float4*)(ms + t * 68 + gj0);
    ga[0][0] = fmaf(a.x, bb.x, ga[0][0]); ga[0][1] = fmaf(a.x, bb.y, ga[0][1]);
    ga[0][2] = fmaf(a.x, bb.z, ga[0][2]); ga[0][3] = fmaf(a.x, bb.w, ga[0][3]);
    ga[1][0] = fmaf(a.y, bb.x, ga[1][0]); ga[1][1] = fmaf(a.y, bb.y, ga[1][1]);
    ga[1][2] = fmaf(a.y, bb.z, ga[1][2]); ga[1][3] = fmaf(a.y, bb.w, ga[1][3]);
    ga[2][0] = fmaf(a.z, bb.x, ga[2][0]); ga[2][1] = fmaf(a.z, bb.y, ga[2][1]);
    ga[2][2] = fmaf(a.z, bb.z, ga[2][2]); ga[2][3] = fmaf(a.z, bb.w, ga[2][3]);
    ga[3][0] = fmaf(a.w, bb.x, ga[3][0]); ga[3][1] = fmaf(a.w, bb.y, ga[3][1]);
    ga[3][2] = fmaf(a.w, bb.z, ga[3][2]); ga[3][3] = fmaf(a.w, bb.w, ga[3][3]);
  }
  u64* slot = CmAcc + (size_t)(bid & 3) * 4096;
#pragma unroll
  for (int ii = 0; ii < 4; ii++)
#pragma unroll
    for (int jj = 0; jj < 4; jj++)
      atomicAdd(slot + (gi0 + ii) * 64 + gj0 + jj, to_fx(ga[ii][jj]));
}

// ---------------- K3: correction + softmax2 -> M0; emit P0 ------------------
__launch_bounds__(256)
__global__ void k_correct(const float* __restrict__ Lbuf, const u64* __restrict__ CmAcc,
                          float* __restrict__ M0, u64* __restrict__ p0Acc) {
  __shared__ float ms[64 * 68];
  __shared__ float Cs[4096];
  __shared__ float cred[256];
  const int tid = threadIdx.x, bid = blockIdx.x;
  const int tg = tid >> 2, q = tid & 3;
  const int lane = tid & 63, w = tid >> 6;
  const int row = bid * 64 + tg;
  float l[16], m[16];
#pragma unroll
  for (int i = 0; i < 4; i++) {
    float4 lv = *(const float4*)(Lbuf + (size_t)row * NE + q * 16 + i * 4);
    l[i * 4 + 0] = lv.x; l[i * 4 + 1] = lv.y; l[i * 4 + 2] = lv.z; l[i * 4 + 3] = lv.w;
  }
  {
    float mx = -1e30f;
#pragma unroll
    for (int j = 0; j < 16; j++) mx = fmaxf(mx, l[j]);
    mx = warp4_max(mx);
    float ps = 0.f;
#pragma unroll
    for (int j = 0; j < 16; j++) { m[j] = expf(l[j] - mx); ps += m[j]; }
    ps = warp4_sum(ps);
    const float inv = 1.0f / ps;
#pragma unroll
    for (int j = 0; j < 16; j++) m[j] *= inv;
#pragma unroll
    for (int i = 0; i < 4; i++)
      *(float4*)(ms + tg * 68 + q * 16 + i * 4) =
          make_float4(m[i * 4], m[i * 4 + 1], m[i * 4 + 2], m[i * 4 + 3]);
  }
#pragma unroll 4
  for (int i = 0; i < 16; i++) {
    int idx = tid + i * 256;
    u64 s = CmAcc[idx] + CmAcc[4096 + idx] + CmAcc[8192 + idx] + CmAcc[12288 + idx];
    float v = (float)((double)s * (1.0 / 4294967296.0));
    int r = idx >> 6, c = idx & 63;
    Cs[idx] = (r == c) ? 0.f : v;
  }
  __syncthreads();
  {
    float g[16];
#pragma unroll
    for (int j = 0; j < 16; j++) g[j] = 0.f;
    for (int f = 0; f < 64; f++) {
      float mf = ms[tg * 68 + f];
#pragma unroll
      for (int i = 0; i < 4; i++) {
        float4 cv = *(const float4*)(Cs + f * 64 + q * 16 + i * 4);
        g[i * 4 + 0] = fmaf(mf, cv.x, g[i * 4 + 0]);
        g[i * 4 + 1] = fmaf(mf, cv.y, g[i * 4 + 1]);
        g[i * 4 + 2] = fmaf(mf, cv.z, g[i * 4 + 2]);
        g[i * 4 + 3] = fmaf(mf, cv.w, g[i * 4 + 3]);
      }
    }
    float dot = 0.f;
#pragma unroll
    for (int j = 0; j < 16; j++) { g[j] *= 4.f; dot += m[j] * g[j]; }
    dot = warp4_sum(dot);
    float mx = -1e30f;
#pragma unroll
    for (int j = 0; j < 16; j++) {
      l[j] = l[j] - LTAX * (m[j] * (g[j] - dot));
      mx = fmaxf(mx, l[j]);
    }
    mx = warp4_max(mx);
    float ps = 0.f;
#pragma unroll
    for (int j = 0; j < 16; j++) { m[j] = expf(l[j] - mx); ps += m[j]; }
    ps = warp4_sum(ps);
    const float inv = 1.0f / ps;
#pragma unroll
    for (int j = 0; j < 16; j++) m[j] *= inv;
#pragma unroll
    for (int i = 0; i < 4; i++)
      *(float4*)(M0 + (size_t)row * NE + q * 16 + i * 4) =
          make_float4(m[i * 4], m[i * 4 + 1], m[i * 4 + 2], m[i * 4 + 3]);
  }
  {
    float cs[16];
#pragma unroll
    for (int j = 0; j < 16; j++) cs[j] = m[j];
#pragma unroll
    for (int j = 0; j < 16; j++) {
      cs[j] += __shfl_xor(cs[j], 4);  cs[j] += __shfl_xor(cs[j], 8);
      cs[j] += __shfl_xor(cs[j], 16); cs[j] += __shfl_xor(cs[j], 32);
    }
    if ((lane >> 2) == 0) {
#pragma unroll
      for (int j = 0; j < 16; j++) cred[w * 64 + lane * 16 + j] = cs[j];
    }
    __syncthreads();
    if (tid < 64)
      atomicAdd(p0Acc + (size_t)(bid & 15) * 64 + tid,
                to_fx(cred[tid] + cred[64 + tid] + cred[128 + tid] + cred[192 + tid]));
  }
}

// ---------------- K4: one factored Sinkhorn iteration -----------------------
__launch_bounds__(256)
__global__ void k_sink(const float* __restrict__ M0, const u64* __restrict__ pin,
                       u64* __restrict__ pout) {
  __shared__ u64 pred[4][64];
  __shared__ float fac[64];
  __shared__ float cred[256];
  const int tid = threadIdx.x, bid = blockIdx.x;
  const int tg = tid >> 2, q = tid & 3;
  const int lane = tid & 63, w = tid >> 6;
  const int row = bid * 64 + tg;
  {
    const int grp = tid >> 6, e = tid & 63;
    pred[grp][e] = pin[grp * 64 + e] + pin[(grp + 4) * 64 + e] +
                   pin[(grp + 8) * 64 + e] + pin[(grp + 12) * 64 + e];
  }
  __syncthreads();
  if (tid < 64) {
    u64 s = pred[0][tid] + pred[1][tid] + pred[2][tid] + pred[3][tid];
    float P = (float)((double)s * (1.0 / 4294967296.0));
    fac[tid] = 256.0f / fmaxf(P, 1e-30f);     // V(e)
  }
  __syncthreads();
  float mv[16];
#pragma unroll
  for (int i = 0; i < 4; i++) {
    float4 v = *(const float4*)(M0 + (size_t)row * NE + q * 16 + i * 4);
    mv[i * 4 + 0] = v.x; mv[i * 4 + 1] = v.y; mv[i * 4 + 2] = v.z; mv[i * 4 + 3] = v.w;
  }
  float Q = 0.f;
#pragma unroll
  for (int j = 0; j < 16; j++) Q = fmaf(mv[j], fac[q * 16 + j], Q);
  Q = warp4_sum(Q);
  const float U = 1.0f / fmaxf(Q, 1e-30f);
  float cs[16];
#pragma unroll
  for (int j = 0; j < 16; j++) cs[j] = U * mv[j];
#pragma unroll
  for (int j = 0; j < 16; j++) {
    cs[j] += __shfl_xor(cs[j], 4);  cs[j] += __shfl_xor(cs[j], 8);
    cs[j] += __shfl_xor(cs[j], 16); cs[j] += __shfl_xor(cs[j], 32);
  }
  if ((lane >> 2) == 0) {
#pragma unroll
    for (int j = 0; j < 16; j++) cred[w * 64 + lane * 16 + j] = cs[j];
  }
  __syncthreads();
  if (tid < 64)
    atomicAdd(pout + (size_t)(bid & 15) * 64 + tid,
              to_fx(cred[tid] + cred[64 + tid] + cred[128 + tid] + cred[192 + tid]));
}

// ---------------- K5: final M10 + damping + hysteresis + topk ---------------
__launch_bounds__(256)
__global__ void k_final(const float* __restrict__ M0, const u64* __restrict__ pin,
                        const float* __restrict__ pp, const void* __restrict__ pmask,
                        float* __restrict__ out) {
  __shared__ u64 pred[4][64];
  __shared__ float fac[64];
  __shared__ int s_cnt[256];
  __shared__ int s_flag;
  const int tid = threadIdx.x, bid = blockIdx.x;
  const int tg = tid >> 2, q = tid & 3;
  const int lane = tid & 63;
  const int row = bid * 64 + tg;

  {
    uint4 v = ((const uint4*)pmask)[tid];
    int c = 0; u32 ww;
    ww = v.x; c += ((ww & 0xffu) != 0) + ((ww & 0xff00u) != 0) + ((ww & 0xff0000u) != 0) + ((ww & 0xff000000u) != 0);
    ww = v.y; c += ((ww & 0xffu) != 0) + ((ww & 0xff00u) != 0) + ((ww & 0xff0000u) != 0) + ((ww & 0xff000000u) != 0);
    ww = v.z; c += ((ww & 0xffu) != 0) + ((ww & 0xff00u) != 0) + ((ww & 0xff0000u) != 0) + ((ww & 0xff000000u) != 0);
    ww = v.w; c += ((ww & 0xffu) != 0) + ((ww & 0xff00u) != 0) + ((ww & 0xff0000u) != 0) + ((ww & 0xff000000u) != 0);
    s_cnt[tid] = c;
    __syncthreads();
    for (int s = 128; s; s >>= 1) { if (tid < s) s_cnt[tid] += s_cnt[tid + s]; __syncthreads(); }
    if (tid == 0) { int n = s_cnt[0]; s_flag = (n > 384) ? 0 : ((n > 192) ? 2 : 1); }
  }
  {
    const int grp = tid >> 6, e = tid & 63;
    pred[grp][e] = pin[grp * 64 + e] + pin[(grp + 4) * 64 + e] +
                   pin[(grp + 8) * 64 + e] + pin[(grp + 12) * 64 + e];
  }
  __syncthreads();
  if (tid < 64) {
    u64 s = pred[0][tid] + pred[1][tid] + pred[2][tid] + pred[3][tid];
    float P = (float)((double)s * (1.0 / 4294967296.0));
    fac[tid] = 256.0f / fmaxf(P, 1e-30f);     // V10
  }
  __syncthreads();

  float mv[16];
#pragma unroll
  for (int i = 0; i < 4; i++) {
    float4 v = *(const float4*)(M0 + (size_t)row * NE + q * 16 + i * 4);
    mv[i * 4 + 0] = v.x; mv[i * 4 + 1] = v.y; mv[i * 4 + 2] = v.z; mv[i * 4 + 3] = v.w;
  }
  float Q = 0.f;
#pragma unroll
  for (int j = 0; j < 16; j++) Q = fmaf(mv[j], fac[q * 16 + j], Q);
  Q = warp4_sum(Q);
  const float U = 1.0f / fmaxf(Q, 1e-30f);
  float m[16];
#pragma unroll
  for (int j = 0; j < 16; j++) m[j] = U * mv[j] * fac[q * 16 + j];   // M10 row

  const int flag = s_flag;
  float pv[16], mk[16];
#pragma unroll
  for (int i = 0; i < 4; i++) {
    float4 v = *(const float4*)(pp + (size_t)row * NE + q * 16 + i * 4);
    pv[i * 4 + 0] = v.x; pv[i * 4 + 1] = v.y; pv[i * 4 + 2] = v.z; pv[i * 4 + 3] = v.w;
  }
  if (flag == 0) {
    const u32* pb = (const u32*)pmask + row * 16 + q * 4;
#pragma unroll
    for (int i = 0; i < 4; i++) {
      u32 ww = pb[i];
      mk[i * 4 + 0] = (ww & 0xffu) ? 1.f : 0.f;
      mk[i * 4 + 1] = (ww & 0xff00u) ? 1.f : 0.f;
      mk[i * 4 + 2] = (ww & 0xff0000u) ? 1.f : 0.f;
      mk[i * 4 + 3] = (ww & 0xff000000u) ? 1.f : 0.f;
    }
  } else if (flag == 1) {
    const int* pb = (const int*)pmask + (size_t)row * NE + q * 16;
#pragma unroll
    for (int j = 0; j < 16; j++) mk[j] = pb[j] ? 1.f : 0.f;
  } else {
    const float* pb = (const float*)pmask + (size_t)row * NE + q * 16;
#pragma unroll
    for (int j = 0; j < 16; j++) mk[j] = (pb[j] != 0.f) ? 1.f : 0.f;
  }
  float msum = 0.f;
#pragma unroll
  for (int j = 0; j < 16; j++) msum += mk[j];
  msum = warp4_sum(msum);
  const float hscale = HYST / fmaxf(msum, 1.0f);
  float v[16];
  float s = 0.f;
#pragma unroll
  for (int j = 0; j < 16; j++) {
    float base = (1.f - ALPHA) * pv[j] + ALPHA * m[j];
    v[j] = (1.f - HYST) * base + hscale * mk[j];
    s += v[j];
  }
  s = warp4_sum(s);
  const float inv = 1.0f / fmaxf(s, 1e-12f);
#pragma unroll
  for (int j = 0; j < 16; j++) v[j] *= inv;

  float* mout = out;
  float* kout = out + (size_t)NT * NE;
#pragma unroll
  for (int i = 0; i < 4; i++)
    *(float4*)(mout + (size_t)row * NE + q * 16 + i * 4) =
        make_float4(v[i * 4], v[i * 4 + 1], v[i * 4 + 2], v[i * 4 + 3]);

  int cnt[16];
#pragma unroll
  for (int j = 0; j < 16; j++) cnt[j] = 0;
  const int base = lane & ~3;
#pragma unroll
  for (int oq = 0; oq < 4; oq++) {
#pragma unroll
    for (int j2 = 0; j2 < 16; j2++) {
      float ov = __shfl(v[j2], base + oq, 64);
      int oe = oq * 16 + j2;
#pragma unroll
      for (int j = 0; j < 16; j++) {
        int me = q * 16 + j;
        if (ov > v[j] || (ov == v[j] && oe < me)) cnt[j]++;
      }
    }
  }
#pragma unroll
  for (int i = 0; i < 4; i++)
    *(float4*)(kout + (size_t)row * NE + q * 16 + i * 4) =
        make_float4(cnt[i * 4] < TOPK ? 1.f : 0.f, cnt[i * 4 + 1] < TOPK ? 1.f : 0.f,
                    cnt[i * 4 + 2] < TOPK ? 1.f : 0.f, cnt[i * 4 + 3] < TOPK ? 1.f : 0.f);
}

extern "C" void kernel_launch(void* const* d_in, const int* in_sizes, int n_in,
                              void* d_out, int out_size, void* d_ws, size_t ws_size,
                              hipStream_t stream) {
  const float* x = (const float*)d_in[0];
  const float* W = (const float*)d_in[1];
  const float* b = (const float*)d_in[2];
  const float* pp = (const float*)d_in[3];
  const void* pmask = d_in[4];
  float* out = (float*)d_out;

  unsigned char* wsb = (unsigned char*)d_ws;
  u16* Wh = (u16*)(wsb);                          // 256 KB
  u16* Wm = (u16*)(wsb + 262144);                 // 256 KB
  u16* Wl = (u16*)(wsb + 524288);                 // 256 KB
  float* Lpart = (float*)(wsb + 786432);          // 8 slices * 4 MB = 32 MB
  float* Lbuf = (float*)(wsb + 34340864);         // 4 MB
  float* M0buf = (float*)(wsb + 38535168);        // 4 MB
  u64* CmAcc = (u64*)(wsb + 42729472);            // 128 KB
  u64* pAcc = (u64*)(wsb + 42860544);             // 80 KB

  k_init<<<232, 256, 0, stream>>>(W, Wh, Wm, Wl, CmAcc);   // split W + zero acc
  k_gemm<<<2048, 256, 0, stream>>>(x, Wh, Wm, Wl, Lpart);
  k_post<<<256, 256, 0, stream>>>(Lpart, b, Lbuf, CmAcc);
  k_correct<<<256, 256, 0, stream>>>(Lbuf, CmAcc, M0buf, pAcc);
  for (int k = 1; k <= 9; k++)
    k_sink<<<256, 256, 0, stream>>>(M0buf, pAcc + (size_t)(k - 1) * 1024,
                                    pAcc + (size_t)k * 1024);
  k_final<<<256, 256, 0, stream>>>(M0buf, pAcc + (size_t)9 * 1024, pp, pmask, out);
}